// Round 7
// baseline (611.120 us; speedup 1.0000x reference)
//
#include <hip/hip_runtime.h>

#define NNODES 100000
#define NEDGES 3200000
#define NF 13
#define NFP 16       // padded f16 row stride for x
#define NG 512
#define BN_EPS 1e-5f
#define NTILES (NNODES / 16)   // 6250 exactly
#define CAP 72       // padded CSR slots per node (deg ~ Poisson(32); P(deg>72) ~ 1e-9)

#define NCHUNK ((NNODES + 63) / 64)    // 1563 64-node chunks
#define NPTASK (3 * NCHUNK)            // wave-tasks for pooling

typedef __attribute__((ext_vector_type(8))) _Float16 f16x8;
typedef __attribute__((ext_vector_type(4))) _Float16 f16x4;
typedef __attribute__((ext_vector_type(4))) float f32x4;

__device__ __forceinline__ unsigned short f2h(float f) {
    union { _Float16 h; unsigned short u; } c;
    c.h = (_Float16)f;   // v_cvt_f16_f32, RNE
    return c.u;
}
__device__ __forceinline__ float h2f(unsigned short u) {
    union { _Float16 h; unsigned short u; } c;
    c.u = u;
    return (float)c.h;   // v_cvt_f32_f16
}

// packed-f16 cross-lane xor-shuffles (shuffle the dwords, add packed)
__device__ __forceinline__ f16x8 shfl_xor8(f16x8 v, int m) {
    union { f16x8 h; int i[4]; } a, b;
    a.h = v;
#pragma unroll
    for (int k = 0; k < 4; ++k) b.i[k] = __shfl_xor(a.i[k], m, 64);
    return b.h;
}
__device__ __forceinline__ f16x4 shfl_xor4(f16x4 v, int m) {
    union { f16x4 h; int i[2]; } a, b;
    a.h = v;
#pragma unroll
    for (int k = 0; k < 2; ++k) b.i[k] = __shfl_xor(a.i[k], m, 64);
    return b.h;
}

// ---------------- direct CSR build: one kernel, global atomic cursors -----------------
// pos = atomicAdd(cnt[dst]); csr[dst*CAP+pos] = src. Replaces the 2-phase bucket
// partition + scatter (pairbuf write-allocate traffic + extra kernel + re-read).
__launch_bounds__(256)
__global__ void build_csr_kernel(const int* __restrict__ src, const int* __restrict__ dst,
                                 int* __restrict__ cnt, int* __restrict__ csr) {
    int idx = blockIdx.x * blockDim.x + threadIdx.x;
    int stride = gridDim.x * blockDim.x;
    for (int e = idx; e < NEDGES; e += stride) {
        int d = __builtin_nontemporal_load(dst + e);
        int s = __builtin_nontemporal_load(src + e);
        int pos = atomicAdd(&cnt[d], 1);
        if (pos < CAP) csr[(size_t)d * CAP + pos] = s;   // clamp: never corrupt neighbors
    }
}

// ---------------- prep: weight MFMA fragments (blocks 0..11) | x conversion -----------
#define CVTB 200
__launch_bounds__(256)
__global__ void prep_kernel(const float* __restrict__ x, unsigned short* __restrict__ xh,
                            const float* __restrict__ w10, const float* __restrict__ w20,
                            const float* __restrict__ w11, const float* __restrict__ w21,
                            const float* __restrict__ w12, const float* __restrict__ w22,
                            unsigned short* __restrict__ wfrag) {
    int bid = blockIdx.x;
    int t = threadIdx.x;
    if (bid < 12) {
        // ---- build MFMA B-fragments for all layer weights (f16) ----
        int tid = bid * 256 + t;  // 3072 total
        if (tid >= 3072) return;
        int layer = tid >> 10;
        int rem = tid & 1023;
        int mat = rem >> 9;
        int tile = (rem >> 7) & 3;
        int chunk = (rem >> 6) & 1;
        int lane = rem & 63;
        int quad = lane >> 4, n = lane & 15;
        const float* W = (layer == 0) ? (mat ? w20 : w10)
                       : (layer == 1) ? (mat ? w21 : w11)
                                      : (mat ? w22 : w12);
        int K = (layer == 0 && mat == 0) ? NF : 64;
        unsigned short* o = wfrag + ((size_t)tid) * 8;
#pragma unroll
        for (int j = 0; j < 8; ++j) {
            int k = chunk * 32 + quad * 8 + j;
            float val = (k < K) ? W[k * 64 + tile * 16 + n] : 0.f;
            o[j] = f2h(val);
        }
    } else {
        // ---- convert x (fp32, stride 13) -> xh (f16, stride 16, zero-padded) ----
        const int total = NNODES * NFP;
        int idx = (bid - 12) * 256 + t;
        int stride = CVTB * 256;
        for (int i = idx; i < total; i += stride) {
            int n = i >> 4;
            int f = i & 15;
            xh[i] = (f < NF) ? f2h(__builtin_nontemporal_load(x + n * NF + f))
                             : (unsigned short)0;
        }
    }
}

// ---------------- fused GIN layer: pair-gather + MFMA MLP through LDS -----------------
// One block = 16 nodes. Wave wid aggregates local nodes wid*4..wid*4+3 (two
// interleaved pairs) into ytile, barrier, then computes output tile t=wid of the
// 2-layer MLP (BN+ReLU between) entirely in LDS/registers.
template <int LAYER>   // 1: fin=13 (xh, stride 16, K=32); 2: fin=64 (h, stride 64, K=64)
__launch_bounds__(256, 4)
__global__ void gin_layer_kernel(const unsigned short* __restrict__ xin,
                                 const int* __restrict__ cnt,
                                 const int* __restrict__ csr,
                                 const unsigned short* __restrict__ wfrag,
                                 const float* __restrict__ b1, const float* __restrict__ gam,
                                 const float* __restrict__ be, const float* __restrict__ mu,
                                 const float* __restrict__ var, const float* __restrict__ b2,
                                 unsigned short* __restrict__ hout) {
    constexpr int FSTR = (LAYER == 1) ? NFP : 64;
    __shared__ __align__(16) unsigned short ytile[16][80];  // agg rows, 160B stride
    __shared__ __align__(16) unsigned short ztile[16][80];  // hidden rows
    int lane = threadIdx.x & 63;
    int wid = threadIdx.x >> 6;
    int quad = lane >> 4, n16 = lane & 15;
    int nb = blockIdx.x * 16;

    // ---------------- aggregation phase ----------------
    if constexpr (LAYER == 1) {
        int g = lane >> 2;   // edge slot within 16-edge gather
        int r = lane & 3;    // row chunk: features r*4 .. r*4+3
#pragma unroll
        for (int pp = 0; pp < 2; ++pp) {
            int lnA = wid * 4 + pp * 2;
            int nA = nb + lnA, nB = nA + 1;
            int dA = __builtin_nontemporal_load(cnt + nA);
            int dB = __builtin_nontemporal_load(cnt + nB);
            if (dA > CAP) dA = CAP;
            if (dB > CAP) dB = CAP;
            int jA = nA * CAP, jB = nB * CAP;
            int endA = jA + dA, endB = jB + dB;
            f16x4 accA = {0, 0, 0, 0};
            f16x4 accB = {0, 0, 0, 0};
            if (g == 0) {  // self rows, added once
                accA = *(const f16x4*)&xin[(size_t)nA * FSTR + r * 4];
                accB = *(const f16x4*)&xin[(size_t)nB * FSTR + r * 4];
            }
            while (jA + 16 <= endA && jB + 16 <= endB) {
                int iA = __builtin_nontemporal_load(csr + jA + g);
                int iB = __builtin_nontemporal_load(csr + jB + g);
                f16x4 vA = *(const f16x4*)&xin[(size_t)iA * FSTR + r * 4];
                f16x4 vB = *(const f16x4*)&xin[(size_t)iB * FSTR + r * 4];
                accA += vA; accB += vB;
                jA += 16; jB += 16;
            }
            for (; jA + 32 <= endA; jA += 32) {
                int i0 = __builtin_nontemporal_load(csr + jA + g);
                int i1 = __builtin_nontemporal_load(csr + jA + 16 + g);
                f16x4 v0 = *(const f16x4*)&xin[(size_t)i0 * FSTR + r * 4];
                f16x4 v1 = *(const f16x4*)&xin[(size_t)i1 * FSTR + r * 4];
                accA += v0; accA += v1;
            }
            for (; jA < endA; jA += 16) {
                int e = jA + g;
                if (e < endA) {
                    int i0 = __builtin_nontemporal_load(csr + e);
                    accA += *(const f16x4*)&xin[(size_t)i0 * FSTR + r * 4];
                }
            }
            for (; jB + 32 <= endB; jB += 32) {
                int i0 = __builtin_nontemporal_load(csr + jB + g);
                int i1 = __builtin_nontemporal_load(csr + jB + 16 + g);
                f16x4 v0 = *(const f16x4*)&xin[(size_t)i0 * FSTR + r * 4];
                f16x4 v1 = *(const f16x4*)&xin[(size_t)i1 * FSTR + r * 4];
                accB += v0; accB += v1;
            }
            for (; jB < endB; jB += 16) {
                int e = jB + g;
                if (e < endB) {
                    int i0 = __builtin_nontemporal_load(csr + e);
                    accB += *(const f16x4*)&xin[(size_t)i0 * FSTR + r * 4];
                }
            }
#pragma unroll
            for (int m = 4; m < 64; m <<= 1) {
                accA += shfl_xor4(accA, m);
                accB += shfl_xor4(accB, m);
            }
            if (g == 0) {
                *(f16x4*)&ytile[lnA][r * 4] = accA;
                *(f16x4*)&ytile[lnA + 1][r * 4] = accB;
            } else if (g == 1) {  // zero-pad cols 16..31 (K=32 MFMA chunk)
                f16x4 z = {0, 0, 0, 0};
                *(f16x4*)&ytile[lnA][16 + r * 4] = z;
                *(f16x4*)&ytile[lnA + 1][16 + r * 4] = z;
            }
        }
    } else {
        int g = lane >> 3;   // edge slot within 8-edge gather
        int r = lane & 7;    // row chunk: features r*8 .. r*8+7
#pragma unroll
        for (int pp = 0; pp < 2; ++pp) {
            int lnA = wid * 4 + pp * 2;
            int nA = nb + lnA, nB = nA + 1;
            int dA = __builtin_nontemporal_load(cnt + nA);
            int dB = __builtin_nontemporal_load(cnt + nB);
            if (dA > CAP) dA = CAP;
            if (dB > CAP) dB = CAP;
            int jA = nA * CAP, jB = nB * CAP;
            int endA = jA + dA, endB = jB + dB;
            f16x8 accA = {0, 0, 0, 0, 0, 0, 0, 0};
            f16x8 accB = {0, 0, 0, 0, 0, 0, 0, 0};
            if (g == 0) {  // self rows, added once
                accA = *(const f16x8*)&xin[(size_t)nA * 64 + r * 8];
                accB = *(const f16x8*)&xin[(size_t)nB * 64 + r * 8];
            }
            while (jA + 16 <= endA && jB + 16 <= endB) {
                int iA0 = __builtin_nontemporal_load(csr + jA + g);
                int iA1 = __builtin_nontemporal_load(csr + jA + 8 + g);
                int iB0 = __builtin_nontemporal_load(csr + jB + g);
                int iB1 = __builtin_nontemporal_load(csr + jB + 8 + g);
                f16x8 vA0 = *(const f16x8*)&xin[(size_t)iA0 * 64 + r * 8];
                f16x8 vA1 = *(const f16x8*)&xin[(size_t)iA1 * 64 + r * 8];
                f16x8 vB0 = *(const f16x8*)&xin[(size_t)iB0 * 64 + r * 8];
                f16x8 vB1 = *(const f16x8*)&xin[(size_t)iB1 * 64 + r * 8];
                accA += vA0; accA += vA1;
                accB += vB0; accB += vB1;
                jA += 16; jB += 16;
            }
            for (; jA + 16 <= endA; jA += 16) {
                int i0 = __builtin_nontemporal_load(csr + jA + g);
                int i1 = __builtin_nontemporal_load(csr + jA + 8 + g);
                f16x8 v0 = *(const f16x8*)&xin[(size_t)i0 * 64 + r * 8];
                f16x8 v1 = *(const f16x8*)&xin[(size_t)i1 * 64 + r * 8];
                accA += v0; accA += v1;
            }
            for (; jA < endA; jA += 8) {
                int e = jA + g;
                if (e < endA) {
                    int i0 = __builtin_nontemporal_load(csr + e);
                    accA += *(const f16x8*)&xin[(size_t)i0 * 64 + r * 8];
                }
            }
            for (; jB + 16 <= endB; jB += 16) {
                int i0 = __builtin_nontemporal_load(csr + jB + g);
                int i1 = __builtin_nontemporal_load(csr + jB + 8 + g);
                f16x8 v0 = *(const f16x8*)&xin[(size_t)i0 * 64 + r * 8];
                f16x8 v1 = *(const f16x8*)&xin[(size_t)i1 * 64 + r * 8];
                accB += v0; accB += v1;
            }
            for (; jB < endB; jB += 8) {
                int e = jB + g;
                if (e < endB) {
                    int i0 = __builtin_nontemporal_load(csr + e);
                    accB += *(const f16x8*)&xin[(size_t)i0 * 64 + r * 8];
                }
            }
#pragma unroll
            for (int m = 8; m < 64; m <<= 1) {
                accA += shfl_xor8(accA, m);
                accB += shfl_xor8(accB, m);
            }
            if (g == 0) {
                *(f16x8*)&ytile[lnA][r * 8] = accA;
                *(f16x8*)&ytile[lnA + 1][r * 8] = accB;
            }
        }
    }

    // ---- load per-wave weight fragments + BN constants (L2-hot; overlaps barrier) ----
    const f16x8* wf = (const f16x8*)wfrag;
    f16x8 w1f0 = wf[((0 * 4 + wid) * 2 + 0) * 64 + lane];
    f16x8 w1f1 = (LAYER == 2) ? wf[((0 * 4 + wid) * 2 + 1) * 64 + lane] : w1f0;
    f16x8 w2f0 = wf[((1 * 4 + wid) * 2 + 0) * 64 + lane];
    f16x8 w2f1 = wf[((1 * 4 + wid) * 2 + 1) * 64 + lane];
    int f = wid * 16 + n16;
    float sc = gam[f] * rsqrtf(var[f] + BN_EPS);
    float sh = (b1[f] - mu[f]) * sc + be[f];
    float bb2 = b2[f];

    __syncthreads();

    // ---------------- MLP: Linear1 + BN + ReLU -> ztile ----------------
    f16x8 a0 = *(const f16x8*)&ytile[n16][quad * 8];
    f32x4 z4 = {0.f, 0.f, 0.f, 0.f};
    z4 = __builtin_amdgcn_mfma_f32_16x16x32_f16(a0, w1f0, z4, 0, 0, 0);
    if constexpr (LAYER == 2) {
        f16x8 a1 = *(const f16x8*)&ytile[n16][32 + quad * 8];
        z4 = __builtin_amdgcn_mfma_f32_16x16x32_f16(a1, w1f1, z4, 0, 0, 0);
    }
#pragma unroll
    for (int reg = 0; reg < 4; ++reg) {
        float z = fmaxf(fmaf(z4[reg], sc, sh), 0.f);
        ztile[quad * 4 + reg][wid * 16 + n16] = f2h(z);
    }
    __syncthreads();

    // ---------------- MLP: Linear2 + ReLU -> global h ----------------
    f16x8 az0 = *(const f16x8*)&ztile[n16][quad * 8];
    f16x8 az1 = *(const f16x8*)&ztile[n16][32 + quad * 8];
    f32x4 h4 = {0.f, 0.f, 0.f, 0.f};
    h4 = __builtin_amdgcn_mfma_f32_16x16x32_f16(az0, w2f0, h4, 0, 0, 0);
    h4 = __builtin_amdgcn_mfma_f32_16x16x32_f16(az1, w2f1, h4, 0, 0, 0);
#pragma unroll
    for (int reg = 0; reg < 4; ++reg) {
        float h = fmaxf(h4[reg] + bb2, 0.f);
        hout[(size_t)(nb + quad * 4 + reg) * 64 + wid * 16 + n16] = f2h(h);
    }
}

// ---------------- pooling: one wave per (layer, 64-node chunk) ----------------
__launch_bounds__(256)
__global__ void pool_kernel(const unsigned short* __restrict__ h1,
                            const unsigned short* __restrict__ h2,
                            const unsigned short* __restrict__ h3,
                            const int* __restrict__ batch,
                            float* __restrict__ pool) {
    int task = blockIdx.x * 4 + (threadIdx.x >> 6);
    if (task >= NPTASK) return;
    int lane = threadIdx.x & 63;
    int layer = task / NCHUNK;
    int c = task - layer * NCHUNK;
    int n0 = c * 64;
    int n1 = n0 + 64; if (n1 > NNODES) n1 = NNODES;
    const unsigned short* hb = (layer == 0) ? h1 : (layer == 1) ? h2 : h3;
    float acc = 0.f;
    int curg = batch[n0];
    for (int n = n0; n < n1; ++n) {
        int gid = batch[n];
        if (gid != curg) {
            atomicAdd(&pool[(size_t)curg * 192 + layer * 64 + lane], acc);
            acc = 0.f;
            curg = gid;
        }
        acc += h2f(__builtin_nontemporal_load(hb + (size_t)n * 64 + lane));
    }
    atomicAdd(&pool[(size_t)curg * 192 + layer * 64 + lane], acc);
}

// ---------------- FC head on pooled features ----------------
__global__ void head_kernel(const float* __restrict__ pool,
                            const float* __restrict__ fc1W, const float* __restrict__ fc1b,
                            const float* __restrict__ fc2W, const float* __restrict__ fc2b,
                            float* __restrict__ out) {
    __shared__ float ps[192];
    __shared__ float hs[192];
    int gi = blockIdx.x;
    int t = threadIdx.x;  // 192
    ps[t] = pool[gi * 192 + t];
    __syncthreads();
    float acc = fc1b[t];
#pragma unroll 8
    for (int k = 0; k < 192; ++k) acc = fmaf(ps[k], fc1W[k * 192 + t], acc);
    hs[t] = fmaxf(acc, 0.f);
    __syncthreads();
    if (t == 0) {
        float l0 = fc2b[0], l1 = fc2b[1];
        for (int k = 0; k < 192; ++k) {
            float h = hs[k];
            l0 = fmaf(h, fc2W[k * 2 + 0], l0);
            l1 = fmaf(h, fc2W[k * 2 + 1], l1);
        }
        float mx = fmaxf(l0, l1);
        float lse = mx + logf(expf(l0 - mx) + expf(l1 - mx));
        out[gi * 2 + 0] = l0 - lse;
        out[gi * 2 + 1] = l1 - lse;
    }
}

extern "C" void kernel_launch(void* const* d_in, const int* in_sizes, int n_in,
                              void* d_out, int out_size, void* d_ws, size_t ws_size,
                              hipStream_t stream) {
    const float* x = (const float*)d_in[0];
    const int* src = (const int*)d_in[1];
    const int* dst = (const int*)d_in[2];
    const int* batch = (const int*)d_in[3];
    const float* c1[8];
    const float* c2[8];
    const float* c3[8];
    for (int i = 0; i < 8; ++i) {
        c1[i] = (const float*)d_in[4 + i];
        c2[i] = (const float*)d_in[12 + i];
        c3[i] = (const float*)d_in[20 + i];
    }
    const float* fc1W = (const float*)d_in[28];
    const float* fc1b = (const float*)d_in[29];
    const float* fc2W = (const float*)d_in[30];
    const float* fc2b = (const float*)d_in[31];
    float* out = (float*)d_out;

    // ---- workspace layout (f16 activations) ----
    unsigned short* base = (unsigned short*)d_ws;
    const size_t NA = (size_t)NNODES * 64;
    unsigned short* xh  = base;                          // N*16
    unsigned short* h1  = xh + (size_t)NNODES * NFP;     // N*64
    unsigned short* h2  = h1 + NA;                       // N*64
    unsigned short* h3  = h2 + NA;                       // N*64
    unsigned short* wfrag = h3 + NA;                     // 3*8192 (16B-aligned)
    float* pool = (float*)(wfrag + 3 * 8192);            // G*192 fp32
    int* ibase = (int*)(pool + (size_t)NG * 192);
    int* cnt = ibase;                                 // N (degree counters)
    int* csr = cnt + NNODES;                          // N*CAP (+pad)

    hipMemsetAsync(cnt, 0, NNODES * sizeof(int), stream);
    hipMemsetAsync(pool, 0, (size_t)NG * 192 * sizeof(float), stream);

    // ---- prep (weight frags + x conversion) and direct atomic CSR build ----
    prep_kernel<<<12 + CVTB, 256, 0, stream>>>(
        x, xh, c1[0], c1[6], c2[0], c2[6], c3[0], c3[6], wfrag);
    build_csr_kernel<<<2048, 256, 0, stream>>>(src, dst, cnt, csr);

    // ---- three fused GIN layers (agg + MLP through LDS) ----
    gin_layer_kernel<1><<<NTILES, 256, 0, stream>>>(
        xh, cnt, csr, wfrag + 0 * 8192,
        c1[1], c1[2], c1[3], c1[4], c1[5], c1[7], h1);
    gin_layer_kernel<2><<<NTILES, 256, 0, stream>>>(
        h1, cnt, csr, wfrag + 1 * 8192,
        c2[1], c2[2], c2[3], c2[4], c2[5], c2[7], h2);
    gin_layer_kernel<2><<<NTILES, 256, 0, stream>>>(
        h2, cnt, csr, wfrag + 2 * 8192,
        c3[1], c3[2], c3[3], c3[4], c3[5], c3[7], h3);

    // ---- pooling (one wave per layer-chunk) + FC head ----
    pool_kernel<<<(NPTASK + 3) / 4, 256, 0, stream>>>(h1, h2, h3, batch, pool);
    head_kernel<<<NG, 192, 0, stream>>>(pool, fc1W, fc1b, fc2W, fc2b, out);
}

// Round 9
// 461.026 us; speedup vs baseline: 1.3256x; 1.3256x over previous
//
#include <hip/hip_runtime.h>

#define NNODES 100000
#define NEDGES 3200000
#define NF 13
#define NFP 16       // padded f16 row stride for x
#define NG 512
#define BN_EPS 1e-5f
#define NTILES (NNODES / 16)   // 6250 exactly
#define CAP 72       // padded CSR slots per node (deg ~ Poisson(32); P(deg>72) ~ 1e-9)

#define BSH 9                          // bucket = 512 dst nodes
#define NBUCK ((NNODES + 511) / 512)   // 196
#define PTILE 4096
#define NPBLK ((NEDGES + PTILE - 1) / PTILE)  // 782
#define EPT (PTILE / 256)              // 16 edges per thread in phase A

#define NCHUNK ((NNODES + 63) / 64)    // 1563 64-node chunks
#define NPTASK (3 * NCHUNK)            // wave-tasks for pooling

typedef __attribute__((ext_vector_type(8))) _Float16 f16x8;
typedef __attribute__((ext_vector_type(4))) _Float16 f16x4;
typedef __attribute__((ext_vector_type(4))) float f32x4;
typedef __attribute__((ext_vector_type(4))) int i32x4;

__device__ __forceinline__ unsigned short f2h(float f) {
    union { _Float16 h; unsigned short u; } c;
    c.h = (_Float16)f;   // v_cvt_f16_f32, RNE
    return c.u;
}
__device__ __forceinline__ float h2f(unsigned short u) {
    union { _Float16 h; unsigned short u; } c;
    c.u = u;
    return (float)c.h;   // v_cvt_f32_f16
}

// packed-f16 cross-lane xor-shuffles (shuffle the dwords, add packed)
__device__ __forceinline__ f16x8 shfl_xor8(f16x8 v, int m) {
    union { f16x8 h; int i[4]; } a, b;
    a.h = v;
#pragma unroll
    for (int k = 0; k < 4; ++k) b.i[k] = __shfl_xor(a.i[k], m, 64);
    return b.h;
}
__device__ __forceinline__ f16x4 shfl_xor4(f16x4 v, int m) {
    union { f16x4 h; int i[2]; } a, b;
    a.h = v;
#pragma unroll
    for (int k = 0; k < 2; ++k) b.i[k] = __shfl_xor(a.i[k], m, 64);
    return b.h;
}

// ---------------- phase A: per-block counting sort by bucket, coalesced writeout ------
// Each block sorts its 4096 edges by 512-node bucket entirely in LDS, then streams the
// sorted pairs to pairout[bid*4096..] with 16B vector stores (zero write-allocate
// waste) and stores a packed (off<<13|cnt) descriptor per (block,bucket).
__launch_bounds__(256)
__global__ void block_sort_kernel(const int* __restrict__ src, const int* __restrict__ dst,
                                  int* __restrict__ pairout, int* __restrict__ bseg) {
    __shared__ int hist[256];      // bucket counts -> cursors
    __shared__ int scanbuf[256];
    __shared__ int spair[PTILE];   // 16 KB sorted pairs
    int t = threadIdx.x;
    int bid = blockIdx.x;
    int base = bid * PTILE;
    int cnt = NEDGES - base; if (cnt > PTILE) cnt = PTILE;

    int v[EPT], b[EPT];
#pragma unroll
    for (int j = 0; j < EPT; ++j) {
        int i = t + j * 256;
        if (i < cnt) {
            int d = __builtin_nontemporal_load(dst + base + i);
            int s = __builtin_nontemporal_load(src + base + i);
            b[j] = d >> BSH;
            v[j] = ((d & 511) << 17) | s;
        } else b[j] = -1;
    }
    hist[t] = 0;
    __syncthreads();
#pragma unroll
    for (int j = 0; j < EPT; ++j)
        if (b[j] >= 0) atomicAdd(&hist[b[j]], 1);
    __syncthreads();
    // exclusive scan over the 256 bucket slots (Hillis-Steele)
    int val = hist[t];
    scanbuf[t] = val;
    __syncthreads();
    for (int off = 1; off < 256; off <<= 1) {
        int add = (t >= off) ? scanbuf[t - off] : 0;
        __syncthreads();
        scanbuf[t] += add;
        __syncthreads();
    }
    int excl = scanbuf[t] - val;   // exclusive prefix
    if (t < NBUCK) bseg[(size_t)bid * NBUCK + t] = (excl << 13) | val;
    hist[t] = excl;                // reuse hist as scatter cursor
    __syncthreads();
#pragma unroll
    for (int j = 0; j < EPT; ++j) {
        if (b[j] >= 0) {
            int pos = atomicAdd(&hist[b[j]], 1);
            spair[pos] = v[j];
        }
    }
    __syncthreads();
    // coalesced 16B writeout of the sorted block
    const i32x4* sp4 = (const i32x4*)spair;
    i32x4* po4 = (i32x4*)(pairout + (size_t)bid * PTILE);
    for (int j = t; j < PTILE / 4; j += 256)
        __builtin_nontemporal_store(sp4[j], po4 + j);
}

// ---------------- phase B: per-bucket segment gather + LDS-cursor scatter -------------
// For bucket bk, walk the 782 per-block segments; csr writes confined to the bucket's
// 512*CAP*4 = 147 KB region (L2-resident for this block), written back once.
__launch_bounds__(512)
__global__ void bucket_gather_kernel(const int* __restrict__ pairout,
                                     const int* __restrict__ bseg,
                                     int* __restrict__ cursor, int* __restrict__ csr) {
    __shared__ int lcnt[512];
    int bk = blockIdx.x;
    int lo = bk << BSH;
    int t = threadIdx.x;
    lcnt[t] = 0;
    __syncthreads();
    for (int k = t; k < NPBLK; k += 512) {
        int pk = bseg[(size_t)k * NBUCK + bk];
        int cnt = pk & 8191;
        const int* seg = pairout + (size_t)k * PTILE + (pk >> 13);
        for (int i = 0; i < cnt; ++i) {
            int p = __builtin_nontemporal_load(seg + i);
            int dl = p >> 17;
            int s = p & 0x1FFFF;
            int pos = atomicAdd(&lcnt[dl], 1);
            if (pos < CAP) csr[(size_t)(lo + dl) * CAP + pos] = s;
        }
    }
    __syncthreads();
    int n = lo + t;
    if (n < NNODES) {
        int d = lcnt[t]; if (d > CAP) d = CAP;
        cursor[n] = n * CAP + d;
    }
}

// ---------------- prep: weight MFMA fragments (blocks 0..11) | x conversion -----------
#define CVTB 200
__launch_bounds__(256)
__global__ void prep_kernel(const float* __restrict__ x, unsigned short* __restrict__ xh,
                            const float* __restrict__ w10, const float* __restrict__ w20,
                            const float* __restrict__ w11, const float* __restrict__ w21,
                            const float* __restrict__ w12, const float* __restrict__ w22,
                            unsigned short* __restrict__ wfrag) {
    int bid = blockIdx.x;
    int t = threadIdx.x;
    if (bid < 12) {
        // ---- build MFMA B-fragments for all layer weights (f16) ----
        int tid = bid * 256 + t;  // 3072 total
        if (tid >= 3072) return;
        int layer = tid >> 10;
        int rem = tid & 1023;
        int mat = rem >> 9;
        int tile = (rem >> 7) & 3;
        int chunk = (rem >> 6) & 1;
        int lane = rem & 63;
        int quad = lane >> 4, n = lane & 15;
        const float* W = (layer == 0) ? (mat ? w20 : w10)
                       : (layer == 1) ? (mat ? w21 : w11)
                                      : (mat ? w22 : w12);
        int K = (layer == 0 && mat == 0) ? NF : 64;
        unsigned short* o = wfrag + ((size_t)tid) * 8;
#pragma unroll
        for (int j = 0; j < 8; ++j) {
            int k = chunk * 32 + quad * 8 + j;
            float val = (k < K) ? W[k * 64 + tile * 16 + n] : 0.f;
            o[j] = f2h(val);
        }
    } else {
        // ---- convert x (fp32, stride 13) -> xh (f16, stride 16, zero-padded) ----
        const int total = NNODES * NFP;
        int idx = (bid - 12) * 256 + t;
        int stride = CVTB * 256;
        for (int i = idx; i < total; i += stride) {
            int n = i >> 4;
            int f = i & 15;
            xh[i] = (f < NF) ? f2h(__builtin_nontemporal_load(x + n * NF + f))
                             : (unsigned short)0;
        }
    }
}

// ---------------- fused GIN layer: pair-gather + MFMA MLP through LDS -----------------
// One block = 16 nodes. Wave wid aggregates local nodes wid*4..wid*4+3 (two
// interleaved pairs) into ytile, barrier, then computes output tile t=wid of the
// 2-layer MLP (BN+ReLU between) entirely in LDS/registers.
template <int LAYER>   // 1: fin=13 (xh, stride 16, K=32); 2: fin=64 (h, stride 64, K=64)
__launch_bounds__(256, 4)
__global__ void gin_layer_kernel(const unsigned short* __restrict__ xin,
                                 const int* __restrict__ cursor,
                                 const int* __restrict__ csr,
                                 const unsigned short* __restrict__ wfrag,
                                 const float* __restrict__ b1, const float* __restrict__ gam,
                                 const float* __restrict__ be, const float* __restrict__ mu,
                                 const float* __restrict__ var, const float* __restrict__ b2,
                                 unsigned short* __restrict__ hout) {
    constexpr int FSTR = (LAYER == 1) ? NFP : 64;
    __shared__ __align__(16) unsigned short ytile[16][80];  // agg rows, 160B stride
    __shared__ __align__(16) unsigned short ztile[16][80];  // hidden rows
    int lane = threadIdx.x & 63;
    int wid = threadIdx.x >> 6;
    int quad = lane >> 4, n16 = lane & 15;
    int nb = blockIdx.x * 16;

    // ---------------- aggregation phase ----------------
    if constexpr (LAYER == 1) {
        int g = lane >> 2;   // edge slot within 16-edge gather
        int r = lane & 3;    // row chunk: features r*4 .. r*4+3
#pragma unroll
        for (int pp = 0; pp < 2; ++pp) {
            int lnA = wid * 4 + pp * 2;
            int nA = nb + lnA, nB = nA + 1;
            int jA = nA * CAP, jB = nB * CAP;
            int endA = cursor[nA], endB = cursor[nB];
            f16x4 accA = {0, 0, 0, 0};
            f16x4 accB = {0, 0, 0, 0};
            if (g == 0) {  // self rows, added once
                accA = *(const f16x4*)&xin[(size_t)nA * FSTR + r * 4];
                accB = *(const f16x4*)&xin[(size_t)nB * FSTR + r * 4];
            }
            while (jA + 16 <= endA && jB + 16 <= endB) {
                int iA = __builtin_nontemporal_load(csr + jA + g);
                int iB = __builtin_nontemporal_load(csr + jB + g);
                f16x4 vA = *(const f16x4*)&xin[(size_t)iA * FSTR + r * 4];
                f16x4 vB = *(const f16x4*)&xin[(size_t)iB * FSTR + r * 4];
                accA += vA; accB += vB;
                jA += 16; jB += 16;
            }
            for (; jA + 32 <= endA; jA += 32) {
                int i0 = __builtin_nontemporal_load(csr + jA + g);
                int i1 = __builtin_nontemporal_load(csr + jA + 16 + g);
                f16x4 v0 = *(const f16x4*)&xin[(size_t)i0 * FSTR + r * 4];
                f16x4 v1 = *(const f16x4*)&xin[(size_t)i1 * FSTR + r * 4];
                accA += v0; accA += v1;
            }
            for (; jA < endA; jA += 16) {
                int e = jA + g;
                if (e < endA) {
                    int i0 = __builtin_nontemporal_load(csr + e);
                    accA += *(const f16x4*)&xin[(size_t)i0 * FSTR + r * 4];
                }
            }
            for (; jB + 32 <= endB; jB += 32) {
                int i0 = __builtin_nontemporal_load(csr + jB + g);
                int i1 = __builtin_nontemporal_load(csr + jB + 16 + g);
                f16x4 v0 = *(const f16x4*)&xin[(size_t)i0 * FSTR + r * 4];
                f16x4 v1 = *(const f16x4*)&xin[(size_t)i1 * FSTR + r * 4];
                accB += v0; accB += v1;
            }
            for (; jB < endB; jB += 16) {
                int e = jB + g;
                if (e < endB) {
                    int i0 = __builtin_nontemporal_load(csr + e);
                    accB += *(const f16x4*)&xin[(size_t)i0 * FSTR + r * 4];
                }
            }
#pragma unroll
            for (int m = 4; m < 64; m <<= 1) {
                accA += shfl_xor4(accA, m);
                accB += shfl_xor4(accB, m);
            }
            if (g == 0) {
                *(f16x4*)&ytile[lnA][r * 4] = accA;
                *(f16x4*)&ytile[lnA + 1][r * 4] = accB;
            } else if (g == 1) {  // zero-pad cols 16..31 (K=32 MFMA chunk)
                f16x4 z = {0, 0, 0, 0};
                *(f16x4*)&ytile[lnA][16 + r * 4] = z;
                *(f16x4*)&ytile[lnA + 1][16 + r * 4] = z;
            }
        }
    } else {
        int g = lane >> 3;   // edge slot within 8-edge gather
        int r = lane & 7;    // row chunk: features r*8 .. r*8+7
#pragma unroll
        for (int pp = 0; pp < 2; ++pp) {
            int lnA = wid * 4 + pp * 2;
            int nA = nb + lnA, nB = nA + 1;
            int jA = nA * CAP, jB = nB * CAP;
            int endA = cursor[nA], endB = cursor[nB];
            f16x8 accA = {0, 0, 0, 0, 0, 0, 0, 0};
            f16x8 accB = {0, 0, 0, 0, 0, 0, 0, 0};
            if (g == 0) {  // self rows, added once
                accA = *(const f16x8*)&xin[(size_t)nA * 64 + r * 8];
                accB = *(const f16x8*)&xin[(size_t)nB * 64 + r * 8];
            }
            while (jA + 16 <= endA && jB + 16 <= endB) {
                int iA0 = __builtin_nontemporal_load(csr + jA + g);
                int iA1 = __builtin_nontemporal_load(csr + jA + 8 + g);
                int iB0 = __builtin_nontemporal_load(csr + jB + g);
                int iB1 = __builtin_nontemporal_load(csr + jB + 8 + g);
                f16x8 vA0 = *(const f16x8*)&xin[(size_t)iA0 * 64 + r * 8];
                f16x8 vA1 = *(const f16x8*)&xin[(size_t)iA1 * 64 + r * 8];
                f16x8 vB0 = *(const f16x8*)&xin[(size_t)iB0 * 64 + r * 8];
                f16x8 vB1 = *(const f16x8*)&xin[(size_t)iB1 * 64 + r * 8];
                accA += vA0; accA += vA1;
                accB += vB0; accB += vB1;
                jA += 16; jB += 16;
            }
            for (; jA + 16 <= endA; jA += 16) {
                int i0 = __builtin_nontemporal_load(csr + jA + g);
                int i1 = __builtin_nontemporal_load(csr + jA + 8 + g);
                f16x8 v0 = *(const f16x8*)&xin[(size_t)i0 * 64 + r * 8];
                f16x8 v1 = *(const f16x8*)&xin[(size_t)i1 * 64 + r * 8];
                accA += v0; accA += v1;
            }
            for (; jA < endA; jA += 8) {
                int e = jA + g;
                if (e < endA) {
                    int i0 = __builtin_nontemporal_load(csr + e);
                    accA += *(const f16x8*)&xin[(size_t)i0 * 64 + r * 8];
                }
            }
            for (; jB + 16 <= endB; jB += 16) {
                int i0 = __builtin_nontemporal_load(csr + jB + g);
                int i1 = __builtin_nontemporal_load(csr + jB + 8 + g);
                f16x8 v0 = *(const f16x8*)&xin[(size_t)i0 * 64 + r * 8];
                f16x8 v1 = *(const f16x8*)&xin[(size_t)i1 * 64 + r * 8];
                accB += v0; accB += v1;
            }
            for (; jB < endB; jB += 8) {
                int e = jB + g;
                if (e < endB) {
                    int i0 = __builtin_nontemporal_load(csr + e);
                    accB += *(const f16x8*)&xin[(size_t)i0 * 64 + r * 8];
                }
            }
#pragma unroll
            for (int m = 8; m < 64; m <<= 1) {
                accA += shfl_xor8(accA, m);
                accB += shfl_xor8(accB, m);
            }
            if (g == 0) {
                *(f16x8*)&ytile[lnA][r * 8] = accA;
                *(f16x8*)&ytile[lnA + 1][r * 8] = accB;
            }
        }
    }

    // ---- load per-wave weight fragments + BN constants (L2-hot; overlaps barrier) ----
    const f16x8* wf = (const f16x8*)wfrag;
    f16x8 w1f0 = wf[((0 * 4 + wid) * 2 + 0) * 64 + lane];
    f16x8 w1f1 = (LAYER == 2) ? wf[((0 * 4 + wid) * 2 + 1) * 64 + lane] : w1f0;
    f16x8 w2f0 = wf[((1 * 4 + wid) * 2 + 0) * 64 + lane];
    f16x8 w2f1 = wf[((1 * 4 + wid) * 2 + 1) * 64 + lane];
    int f = wid * 16 + n16;
    float sc = gam[f] * rsqrtf(var[f] + BN_EPS);
    float sh = (b1[f] - mu[f]) * sc + be[f];
    float bb2 = b2[f];

    __syncthreads();

    // ---------------- MLP: Linear1 + BN + ReLU -> ztile ----------------
    f16x8 a0 = *(const f16x8*)&ytile[n16][quad * 8];
    f32x4 z4 = {0.f, 0.f, 0.f, 0.f};
    z4 = __builtin_amdgcn_mfma_f32_16x16x32_f16(a0, w1f0, z4, 0, 0, 0);
    if constexpr (LAYER == 2) {
        f16x8 a1 = *(const f16x8*)&ytile[n16][32 + quad * 8];
        z4 = __builtin_amdgcn_mfma_f32_16x16x32_f16(a1, w1f1, z4, 0, 0, 0);
    }
#pragma unroll
    for (int reg = 0; reg < 4; ++reg) {
        float z = fmaxf(fmaf(z4[reg], sc, sh), 0.f);
        ztile[quad * 4 + reg][wid * 16 + n16] = f2h(z);
    }
    __syncthreads();

    // ---------------- MLP: Linear2 + ReLU -> global h ----------------
    f16x8 az0 = *(const f16x8*)&ztile[n16][quad * 8];
    f16x8 az1 = *(const f16x8*)&ztile[n16][32 + quad * 8];
    f32x4 h4 = {0.f, 0.f, 0.f, 0.f};
    h4 = __builtin_amdgcn_mfma_f32_16x16x32_f16(az0, w2f0, h4, 0, 0, 0);
    h4 = __builtin_amdgcn_mfma_f32_16x16x32_f16(az1, w2f1, h4, 0, 0, 0);
#pragma unroll
    for (int reg = 0; reg < 4; ++reg) {
        float h = fmaxf(h4[reg] + bb2, 0.f);
        hout[(size_t)(nb + quad * 4 + reg) * 64 + wid * 16 + n16] = f2h(h);
    }
}

// ---------------- pooling: one wave per (layer, 64-node chunk) ----------------
__launch_bounds__(256)
__global__ void pool_kernel(const unsigned short* __restrict__ h1,
                            const unsigned short* __restrict__ h2,
                            const unsigned short* __restrict__ h3,
                            const int* __restrict__ batch,
                            float* __restrict__ pool) {
    int task = blockIdx.x * 4 + (threadIdx.x >> 6);
    if (task >= NPTASK) return;
    int lane = threadIdx.x & 63;
    int layer = task / NCHUNK;
    int c = task - layer * NCHUNK;
    int n0 = c * 64;
    int n1 = n0 + 64; if (n1 > NNODES) n1 = NNODES;
    const unsigned short* hb = (layer == 0) ? h1 : (layer == 1) ? h2 : h3;
    float acc = 0.f;
    int curg = batch[n0];
    for (int n = n0; n < n1; ++n) {
        int gid = batch[n];
        if (gid != curg) {
            atomicAdd(&pool[(size_t)curg * 192 + layer * 64 + lane], acc);
            acc = 0.f;
            curg = gid;
        }
        acc += h2f(__builtin_nontemporal_load(hb + (size_t)n * 64 + lane));
    }
    atomicAdd(&pool[(size_t)curg * 192 + layer * 64 + lane], acc);
}

// ---------------- FC head on pooled features ----------------
__global__ void head_kernel(const float* __restrict__ pool,
                            const float* __restrict__ fc1W, const float* __restrict__ fc1b,
                            const float* __restrict__ fc2W, const float* __restrict__ fc2b,
                            float* __restrict__ out) {
    __shared__ float ps[192];
    __shared__ float hs[192];
    int gi = blockIdx.x;
    int t = threadIdx.x;  // 192
    ps[t] = pool[gi * 192 + t];
    __syncthreads();
    float acc = fc1b[t];
#pragma unroll 8
    for (int k = 0; k < 192; ++k) acc = fmaf(ps[k], fc1W[k * 192 + t], acc);
    hs[t] = fmaxf(acc, 0.f);
    __syncthreads();
    if (t == 0) {
        float l0 = fc2b[0], l1 = fc2b[1];
        for (int k = 0; k < 192; ++k) {
            float h = hs[k];
            l0 = fmaf(h, fc2W[k * 2 + 0], l0);
            l1 = fmaf(h, fc2W[k * 2 + 1], l1);
        }
        float mx = fmaxf(l0, l1);
        float lse = mx + logf(expf(l0 - mx) + expf(l1 - mx));
        out[gi * 2 + 0] = l0 - lse;
        out[gi * 2 + 1] = l1 - lse;
    }
}

extern "C" void kernel_launch(void* const* d_in, const int* in_sizes, int n_in,
                              void* d_out, int out_size, void* d_ws, size_t ws_size,
                              hipStream_t stream) {
    const float* x = (const float*)d_in[0];
    const int* src = (const int*)d_in[1];
    const int* dst = (const int*)d_in[2];
    const int* batch = (const int*)d_in[3];
    const float* c1[8];
    const float* c2[8];
    const float* c3[8];
    for (int i = 0; i < 8; ++i) {
        c1[i] = (const float*)d_in[4 + i];
        c2[i] = (const float*)d_in[12 + i];
        c3[i] = (const float*)d_in[20 + i];
    }
    const float* fc1W = (const float*)d_in[28];
    const float* fc1b = (const float*)d_in[29];
    const float* fc2W = (const float*)d_in[30];
    const float* fc2b = (const float*)d_in[31];
    float* out = (float*)d_out;

    // ---- workspace layout (f16 activations) ----
    unsigned short* base = (unsigned short*)d_ws;
    const size_t NA = (size_t)NNODES * 64;
    unsigned short* xh  = base;                          // N*16
    unsigned short* h1  = xh + (size_t)NNODES * NFP;     // N*64
    unsigned short* h2  = h1 + NA;                       // N*64
    unsigned short* h3  = h2 + NA;                       // N*64
    unsigned short* wfrag = h3 + NA;                     // 3*8192 (16B-aligned)
    float* pool = (float*)(wfrag + 3 * 8192);            // G*192 fp32
    int* ibase = (int*)(pool + (size_t)NG * 192);
    int* cursor  = ibase;                                // N
    int* csr     = cursor + NNODES;                      // N*CAP
    int* pairout = csr + (size_t)NNODES * CAP + 256;     // NPBLK*PTILE (16B-aligned)
    int* bseg    = pairout + (size_t)NPBLK * PTILE;      // NPBLK*NBUCK

    (void)hipMemsetAsync(pool, 0, (size_t)NG * 192 * sizeof(float), stream);

    // ---- CSR build: block counting-sort (coalesced) + per-bucket gather/scatter ----
    block_sort_kernel<<<NPBLK, 256, 0, stream>>>(src, dst, pairout, bseg);
    prep_kernel<<<12 + CVTB, 256, 0, stream>>>(
        x, xh, c1[0], c1[6], c2[0], c2[6], c3[0], c3[6], wfrag);
    bucket_gather_kernel<<<NBUCK, 512, 0, stream>>>(pairout, bseg, cursor, csr);

    // ---- three fused GIN layers (agg + MLP through LDS) ----
    gin_layer_kernel<1><<<NTILES, 256, 0, stream>>>(
        xh, cursor, csr, wfrag + 0 * 8192,
        c1[1], c1[2], c1[3], c1[4], c1[5], c1[7], h1);
    gin_layer_kernel<2><<<NTILES, 256, 0, stream>>>(
        h1, cursor, csr, wfrag + 1 * 8192,
        c2[1], c2[2], c2[3], c2[4], c2[5], c2[7], h2);
    gin_layer_kernel<2><<<NTILES, 256, 0, stream>>>(
        h2, cursor, csr, wfrag + 2 * 8192,
        c3[1], c3[2], c3[3], c3[4], c3[5], c3[7], h3);

    // ---- pooling (one wave per layer-chunk) + FC head ----
    pool_kernel<<<(NPTASK + 3) / 4, 256, 0, stream>>>(h1, h2, h3, batch, pool);
    head_kernel<<<NG, 192, 0, stream>>>(pool, fc1W, fc1b, fc2W, fc2b, out);
}

// Round 10
// 446.440 us; speedup vs baseline: 1.3689x; 1.0327x over previous
//
#include <hip/hip_runtime.h>

#define NNODES 100000
#define NEDGES 3200000
#define NF 13
#define NFP 16       // padded f16 row stride for x
#define NG 512
#define BN_EPS 1e-5f
#define NTILES (NNODES / 16)   // 6250 exactly

#define BSH 9                          // bucket = 512 dst nodes
#define NBUCK ((NNODES + 511) / 512)   // 196
#define PTILE 4096
#define NPBLK ((NEDGES + PTILE - 1) / PTILE)  // 782
#define EPT (PTILE / 256)              // 16 edges per thread in phase A
#define SCAP 17664                     // per-bucket edge cap (mean 16384, +10 sigma)

#define NCHUNK ((NNODES + 63) / 64)    // 1563 64-node chunks
#define NPTASK (3 * NCHUNK)            // wave-tasks for pooling

typedef __attribute__((ext_vector_type(8))) _Float16 f16x8;
typedef __attribute__((ext_vector_type(4))) _Float16 f16x4;
typedef __attribute__((ext_vector_type(4))) float f32x4;
typedef __attribute__((ext_vector_type(4))) int i32x4;

__device__ __forceinline__ unsigned short f2h(float f) {
    union { _Float16 h; unsigned short u; } c;
    c.h = (_Float16)f;   // v_cvt_f16_f32, RNE
    return c.u;
}
__device__ __forceinline__ float h2f(unsigned short u) {
    union { _Float16 h; unsigned short u; } c;
    c.u = u;
    return (float)c.h;   // v_cvt_f32_f16
}

// packed-f16 cross-lane xor-shuffles (shuffle the dwords, add packed)
__device__ __forceinline__ f16x8 shfl_xor8(f16x8 v, int m) {
    union { f16x8 h; int i[4]; } a, b;
    a.h = v;
#pragma unroll
    for (int k = 0; k < 4; ++k) b.i[k] = __shfl_xor(a.i[k], m, 64);
    return b.h;
}
__device__ __forceinline__ f16x4 shfl_xor4(f16x4 v, int m) {
    union { f16x4 h; int i[2]; } a, b;
    a.h = v;
#pragma unroll
    for (int k = 0; k < 2; ++k) b.i[k] = __shfl_xor(a.i[k], m, 64);
    return b.h;
}

// ---------------- phase A: per-block counting sort by bucket, coalesced writeout ------
__launch_bounds__(256)
__global__ void block_sort_kernel(const int* __restrict__ src, const int* __restrict__ dst,
                                  int* __restrict__ pairout, int* __restrict__ bseg,
                                  int* __restrict__ gcount) {
    __shared__ int hist[256];      // bucket counts -> cursors
    __shared__ int scanbuf[256];
    __shared__ int spair[PTILE];   // 16 KB sorted pairs
    int t = threadIdx.x;
    int bid = blockIdx.x;
    int base = bid * PTILE;
    int cnt = NEDGES - base; if (cnt > PTILE) cnt = PTILE;

    int v[EPT], b[EPT];
#pragma unroll
    for (int j = 0; j < EPT; ++j) {
        int i = t + j * 256;
        if (i < cnt) {
            int d = __builtin_nontemporal_load(dst + base + i);
            int s = __builtin_nontemporal_load(src + base + i);
            b[j] = d >> BSH;
            v[j] = ((d & 511) << 17) | s;
        } else b[j] = -1;
    }
    hist[t] = 0;
    __syncthreads();
#pragma unroll
    for (int j = 0; j < EPT; ++j)
        if (b[j] >= 0) atomicAdd(&hist[b[j]], 1);
    __syncthreads();
    // exclusive scan over the 256 bucket slots (Hillis-Steele)
    int val = hist[t];
    scanbuf[t] = val;
    __syncthreads();
    for (int off = 1; off < 256; off <<= 1) {
        int add = (t >= off) ? scanbuf[t - off] : 0;
        __syncthreads();
        scanbuf[t] += add;
        __syncthreads();
    }
    int excl = scanbuf[t] - val;   // exclusive prefix
    if (t < NBUCK) {
        bseg[(size_t)bid * NBUCK + t] = (excl << 13) | val;
        if (val > 0) atomicAdd(&gcount[t], val);
    }
    hist[t] = excl;                // reuse hist as scatter cursor
    __syncthreads();
#pragma unroll
    for (int j = 0; j < EPT; ++j) {
        if (b[j] >= 0) {
            int pos = atomicAdd(&hist[b[j]], 1);
            spair[pos] = v[j];
        }
    }
    __syncthreads();
    // coalesced 16B writeout of the sorted block
    const i32x4* sp4 = (const i32x4*)spair;
    i32x4* po4 = (i32x4*)(pairout + (size_t)bid * PTILE);
    for (int j = t; j < PTILE / 4; j += 256)
        __builtin_nontemporal_store(sp4[j], po4 + j);
}

// ---------------- phase B: per-bucket in-LDS counting sort -> compact CSR -------------
// One 1024-thread block per bucket. Wave-cooperative segment copy into LDS, 512-bin
// histogram + scan (writes rowptr), LDS scatter to sorted order, coalesced writeout.
__launch_bounds__(1024)
__global__ void bucket_sort_kernel(const int* __restrict__ pairout,
                                   const int* __restrict__ bseg,
                                   const int* __restrict__ gcount,
                                   int* __restrict__ rowptr,
                                   int* __restrict__ csre) {
    __shared__ int scanbuf[1024];
    __shared__ int soff[NPBLK];
    __shared__ int hcur[512];
    __shared__ int shv[2];         // [0]=bucket base, [1]=total
    __shared__ int spair[SCAP];
    __shared__ int ssort[SCAP];
    int bk = blockIdx.x;
    int t = threadIdx.x;
    int lo = bk << BSH;
    int wave = t >> 6, lane = t & 63;

    // ---- scan 1: global bucket base from gcount ----
    int gv = (t < NBUCK) ? gcount[t] : 0;
    scanbuf[t] = gv;
    __syncthreads();
    for (int off = 1; off < 1024; off <<= 1) {
        int a = (t >= off) ? scanbuf[t - off] : 0;
        __syncthreads();
        scanbuf[t] += a;
        __syncthreads();
    }
    if (t == bk) shv[0] = scanbuf[t] - gv;   // exclusive prefix at bk
    __syncthreads();

    // ---- scan 2: per-segment LDS offsets ----
    int c = (t < NPBLK) ? (bseg[(size_t)t * NBUCK + bk] & 8191) : 0;
    scanbuf[t] = c;
    __syncthreads();
    for (int off = 1; off < 1024; off <<= 1) {
        int a = (t >= off) ? scanbuf[t - off] : 0;
        __syncthreads();
        scanbuf[t] += a;
        __syncthreads();
    }
    if (t < NPBLK) soff[t] = scanbuf[t] - c;
    if (t == NPBLK - 1) shv[1] = scanbuf[t];
    __syncthreads();
    int bbase = shv[0];
    int total = shv[1]; if (total > SCAP) total = SCAP;

    // ---- wave-cooperative segment copy into spair (coalesced reads) ----
    for (int k = wave; k < NPBLK; k += 16) {
        int pk = bseg[(size_t)k * NBUCK + bk];
        int cnt = pk & 8191;
        const int* seg = pairout + (size_t)k * PTILE + (pk >> 13);
        int dsto = soff[k];
        for (int i = lane; i < cnt; i += 64)
            if (dsto + i < SCAP) spair[dsto + i] = __builtin_nontemporal_load(seg + i);
    }
    if (t < 512) hcur[t] = 0;
    __syncthreads();

    // ---- 512-bin histogram ----
    for (int i = t; i < total; i += 1024) atomicAdd(&hcur[spair[i] >> 17], 1);
    __syncthreads();

    // ---- scan 3: node offsets within bucket; write rowptr ----
    int hv = (t < 512) ? hcur[t] : 0;
    scanbuf[t] = hv;
    __syncthreads();
    for (int off = 1; off < 1024; off <<= 1) {
        int a = (t >= off) ? scanbuf[t - off] : 0;
        __syncthreads();
        scanbuf[t] += a;
        __syncthreads();
    }
    if (t < 512) {
        int excl = scanbuf[t] - hv;
        hcur[t] = excl;
        if (lo + t <= NNODES) rowptr[lo + t] = bbase + excl;
    }
    __syncthreads();

    // ---- LDS scatter into sorted order ----
    for (int i = t; i < total; i += 1024) {
        int p = spair[i];
        int pos = atomicAdd(&hcur[p >> 17], 1);
        ssort[pos] = p & 0x1FFFF;
    }
    __syncthreads();

    // ---- coalesced writeout of the compact per-node edge list ----
    for (int i = t; i < total; i += 1024)
        __builtin_nontemporal_store(ssort[i], csre + bbase + i);
}

// ---------------- prep: weight MFMA fragments (blocks 0..11) | x conversion -----------
#define CVTB 200
__launch_bounds__(256)
__global__ void prep_kernel(const float* __restrict__ x, unsigned short* __restrict__ xh,
                            const float* __restrict__ w10, const float* __restrict__ w20,
                            const float* __restrict__ w11, const float* __restrict__ w21,
                            const float* __restrict__ w12, const float* __restrict__ w22,
                            unsigned short* __restrict__ wfrag) {
    int bid = blockIdx.x;
    int t = threadIdx.x;
    if (bid < 12) {
        // ---- build MFMA B-fragments for all layer weights (f16) ----
        int tid = bid * 256 + t;  // 3072 total
        if (tid >= 3072) return;
        int layer = tid >> 10;
        int rem = tid & 1023;
        int mat = rem >> 9;
        int tile = (rem >> 7) & 3;
        int chunk = (rem >> 6) & 1;
        int lane = rem & 63;
        int quad = lane >> 4, n = lane & 15;
        const float* W = (layer == 0) ? (mat ? w20 : w10)
                       : (layer == 1) ? (mat ? w21 : w11)
                                      : (mat ? w22 : w12);
        int K = (layer == 0 && mat == 0) ? NF : 64;
        unsigned short* o = wfrag + ((size_t)tid) * 8;
#pragma unroll
        for (int j = 0; j < 8; ++j) {
            int k = chunk * 32 + quad * 8 + j;
            float val = (k < K) ? W[k * 64 + tile * 16 + n] : 0.f;
            o[j] = f2h(val);
        }
    } else {
        // ---- convert x (fp32, stride 13) -> xh (f16, stride 16, zero-padded) ----
        const int total = NNODES * NFP;
        int idx = (bid - 12) * 256 + t;
        int stride = CVTB * 256;
        for (int i = idx; i < total; i += stride) {
            int n = i >> 4;
            int f = i & 15;
            xh[i] = (f < NF) ? f2h(__builtin_nontemporal_load(x + n * NF + f))
                             : (unsigned short)0;
        }
    }
}

// ---------------- fused GIN layer: pair-gather + MFMA MLP through LDS -----------------
// One block = 16 nodes; compact CSR via rowptr.
template <int LAYER>   // 1: fin=13 (xh, stride 16, K=32); 2: fin=64 (h, stride 64, K=64)
__launch_bounds__(256, 4)
__global__ void gin_layer_kernel(const unsigned short* __restrict__ xin,
                                 const int* __restrict__ rowptr,
                                 const int* __restrict__ csr,
                                 const unsigned short* __restrict__ wfrag,
                                 const float* __restrict__ b1, const float* __restrict__ gam,
                                 const float* __restrict__ be, const float* __restrict__ mu,
                                 const float* __restrict__ var, const float* __restrict__ b2,
                                 unsigned short* __restrict__ hout) {
    constexpr int FSTR = (LAYER == 1) ? NFP : 64;
    __shared__ __align__(16) unsigned short ytile[16][80];  // agg rows, 160B stride
    __shared__ __align__(16) unsigned short ztile[16][80];  // hidden rows
    int lane = threadIdx.x & 63;
    int wid = threadIdx.x >> 6;
    int quad = lane >> 4, n16 = lane & 15;
    int nb = blockIdx.x * 16;

    // ---------------- aggregation phase ----------------
    if constexpr (LAYER == 1) {
        int g = lane >> 2;   // edge slot within 16-edge gather
        int r = lane & 3;    // row chunk: features r*4 .. r*4+3
#pragma unroll
        for (int pp = 0; pp < 2; ++pp) {
            int lnA = wid * 4 + pp * 2;
            int nA = nb + lnA, nB = nA + 1;
            int jA = rowptr[nA];
            int jB = rowptr[nA + 1];
            int endA = jB;
            int endB = rowptr[nA + 2];
            f16x4 accA = {0, 0, 0, 0};
            f16x4 accB = {0, 0, 0, 0};
            if (g == 0) {  // self rows, added once
                accA = *(const f16x4*)&xin[(size_t)nA * FSTR + r * 4];
                accB = *(const f16x4*)&xin[(size_t)nB * FSTR + r * 4];
            }
            while (jA + 16 <= endA && jB + 16 <= endB) {
                int iA = __builtin_nontemporal_load(csr + jA + g);
                int iB = __builtin_nontemporal_load(csr + jB + g);
                f16x4 vA = *(const f16x4*)&xin[(size_t)iA * FSTR + r * 4];
                f16x4 vB = *(const f16x4*)&xin[(size_t)iB * FSTR + r * 4];
                accA += vA; accB += vB;
                jA += 16; jB += 16;
            }
            for (; jA + 32 <= endA; jA += 32) {
                int i0 = __builtin_nontemporal_load(csr + jA + g);
                int i1 = __builtin_nontemporal_load(csr + jA + 16 + g);
                f16x4 v0 = *(const f16x4*)&xin[(size_t)i0 * FSTR + r * 4];
                f16x4 v1 = *(const f16x4*)&xin[(size_t)i1 * FSTR + r * 4];
                accA += v0; accA += v1;
            }
            for (; jA < endA; jA += 16) {
                int e = jA + g;
                if (e < endA) {
                    int i0 = __builtin_nontemporal_load(csr + e);
                    accA += *(const f16x4*)&xin[(size_t)i0 * FSTR + r * 4];
                }
            }
            for (; jB + 32 <= endB; jB += 32) {
                int i0 = __builtin_nontemporal_load(csr + jB + g);
                int i1 = __builtin_nontemporal_load(csr + jB + 16 + g);
                f16x4 v0 = *(const f16x4*)&xin[(size_t)i0 * FSTR + r * 4];
                f16x4 v1 = *(const f16x4*)&xin[(size_t)i1 * FSTR + r * 4];
                accB += v0; accB += v1;
            }
            for (; jB < endB; jB += 16) {
                int e = jB + g;
                if (e < endB) {
                    int i0 = __builtin_nontemporal_load(csr + e);
                    accB += *(const f16x4*)&xin[(size_t)i0 * FSTR + r * 4];
                }
            }
#pragma unroll
            for (int m = 4; m < 64; m <<= 1) {
                accA += shfl_xor4(accA, m);
                accB += shfl_xor4(accB, m);
            }
            if (g == 0) {
                *(f16x4*)&ytile[lnA][r * 4] = accA;
                *(f16x4*)&ytile[lnA + 1][r * 4] = accB;
            } else if (g == 1) {  // zero-pad cols 16..31 (K=32 MFMA chunk)
                f16x4 z = {0, 0, 0, 0};
                *(f16x4*)&ytile[lnA][16 + r * 4] = z;
                *(f16x4*)&ytile[lnA + 1][16 + r * 4] = z;
            }
        }
    } else {
        int g = lane >> 3;   // edge slot within 8-edge gather
        int r = lane & 7;    // row chunk: features r*8 .. r*8+7
#pragma unroll
        for (int pp = 0; pp < 2; ++pp) {
            int lnA = wid * 4 + pp * 2;
            int nA = nb + lnA, nB = nA + 1;
            int jA = rowptr[nA];
            int jB = rowptr[nA + 1];
            int endA = jB;
            int endB = rowptr[nA + 2];
            f16x8 accA = {0, 0, 0, 0, 0, 0, 0, 0};
            f16x8 accB = {0, 0, 0, 0, 0, 0, 0, 0};
            if (g == 0) {  // self rows, added once
                accA = *(const f16x8*)&xin[(size_t)nA * 64 + r * 8];
                accB = *(const f16x8*)&xin[(size_t)nB * 64 + r * 8];
            }
            while (jA + 16 <= endA && jB + 16 <= endB) {
                int iA0 = __builtin_nontemporal_load(csr + jA + g);
                int iA1 = __builtin_nontemporal_load(csr + jA + 8 + g);
                int iB0 = __builtin_nontemporal_load(csr + jB + g);
                int iB1 = __builtin_nontemporal_load(csr + jB + 8 + g);
                f16x8 vA0 = *(const f16x8*)&xin[(size_t)iA0 * 64 + r * 8];
                f16x8 vA1 = *(const f16x8*)&xin[(size_t)iA1 * 64 + r * 8];
                f16x8 vB0 = *(const f16x8*)&xin[(size_t)iB0 * 64 + r * 8];
                f16x8 vB1 = *(const f16x8*)&xin[(size_t)iB1 * 64 + r * 8];
                accA += vA0; accA += vA1;
                accB += vB0; accB += vB1;
                jA += 16; jB += 16;
            }
            for (; jA + 16 <= endA; jA += 16) {
                int i0 = __builtin_nontemporal_load(csr + jA + g);
                int i1 = __builtin_nontemporal_load(csr + jA + 8 + g);
                f16x8 v0 = *(const f16x8*)&xin[(size_t)i0 * 64 + r * 8];
                f16x8 v1 = *(const f16x8*)&xin[(size_t)i1 * 64 + r * 8];
                accA += v0; accA += v1;
            }
            for (; jA < endA; jA += 8) {
                int e = jA + g;
                if (e < endA) {
                    int i0 = __builtin_nontemporal_load(csr + e);
                    accA += *(const f16x8*)&xin[(size_t)i0 * 64 + r * 8];
                }
            }
            for (; jB + 16 <= endB; jB += 16) {
                int i0 = __builtin_nontemporal_load(csr + jB + g);
                int i1 = __builtin_nontemporal_load(csr + jB + 8 + g);
                f16x8 v0 = *(const f16x8*)&xin[(size_t)i0 * 64 + r * 8];
                f16x8 v1 = *(const f16x8*)&xin[(size_t)i1 * 64 + r * 8];
                accB += v0; accB += v1;
            }
            for (; jB < endB; jB += 8) {
                int e = jB + g;
                if (e < endB) {
                    int i0 = __builtin_nontemporal_load(csr + e);
                    accB += *(const f16x8*)&xin[(size_t)i0 * 64 + r * 8];
                }
            }
#pragma unroll
            for (int m = 8; m < 64; m <<= 1) {
                accA += shfl_xor8(accA, m);
                accB += shfl_xor8(accB, m);
            }
            if (g == 0) {
                *(f16x8*)&ytile[lnA][r * 8] = accA;
                *(f16x8*)&ytile[lnA + 1][r * 8] = accB;
            }
        }
    }

    // ---- load per-wave weight fragments + BN constants (L2-hot; overlaps barrier) ----
    const f16x8* wf = (const f16x8*)wfrag;
    f16x8 w1f0 = wf[((0 * 4 + wid) * 2 + 0) * 64 + lane];
    f16x8 w1f1 = (LAYER == 2) ? wf[((0 * 4 + wid) * 2 + 1) * 64 + lane] : w1f0;
    f16x8 w2f0 = wf[((1 * 4 + wid) * 2 + 0) * 64 + lane];
    f16x8 w2f1 = wf[((1 * 4 + wid) * 2 + 1) * 64 + lane];
    int f = wid * 16 + n16;
    float sc = gam[f] * rsqrtf(var[f] + BN_EPS);
    float sh = (b1[f] - mu[f]) * sc + be[f];
    float bb2 = b2[f];

    __syncthreads();

    // ---------------- MLP: Linear1 + BN + ReLU -> ztile ----------------
    f16x8 a0 = *(const f16x8*)&ytile[n16][quad * 8];
    f32x4 z4 = {0.f, 0.f, 0.f, 0.f};
    z4 = __builtin_amdgcn_mfma_f32_16x16x32_f16(a0, w1f0, z4, 0, 0, 0);
    if constexpr (LAYER == 2) {
        f16x8 a1 = *(const f16x8*)&ytile[n16][32 + quad * 8];
        z4 = __builtin_amdgcn_mfma_f32_16x16x32_f16(a1, w1f1, z4, 0, 0, 0);
    }
#pragma unroll
    for (int reg = 0; reg < 4; ++reg) {
        float z = fmaxf(fmaf(z4[reg], sc, sh), 0.f);
        ztile[quad * 4 + reg][wid * 16 + n16] = f2h(z);
    }
    __syncthreads();

    // ---------------- MLP: Linear2 + ReLU -> global h ----------------
    f16x8 az0 = *(const f16x8*)&ztile[n16][quad * 8];
    f16x8 az1 = *(const f16x8*)&ztile[n16][32 + quad * 8];
    f32x4 h4 = {0.f, 0.f, 0.f, 0.f};
    h4 = __builtin_amdgcn_mfma_f32_16x16x32_f16(az0, w2f0, h4, 0, 0, 0);
    h4 = __builtin_amdgcn_mfma_f32_16x16x32_f16(az1, w2f1, h4, 0, 0, 0);
#pragma unroll
    for (int reg = 0; reg < 4; ++reg) {
        float h = fmaxf(h4[reg] + bb2, 0.f);
        hout[(size_t)(nb + quad * 4 + reg) * 64 + wid * 16 + n16] = f2h(h);
    }
}

// ---------------- pooling: one wave per (layer, 64-node chunk) ----------------
__launch_bounds__(256)
__global__ void pool_kernel(const unsigned short* __restrict__ h1,
                            const unsigned short* __restrict__ h2,
                            const unsigned short* __restrict__ h3,
                            const int* __restrict__ batch,
                            float* __restrict__ pool) {
    int task = blockIdx.x * 4 + (threadIdx.x >> 6);
    if (task >= NPTASK) return;
    int lane = threadIdx.x & 63;
    int layer = task / NCHUNK;
    int c = task - layer * NCHUNK;
    int n0 = c * 64;
    int n1 = n0 + 64; if (n1 > NNODES) n1 = NNODES;
    const unsigned short* hb = (layer == 0) ? h1 : (layer == 1) ? h2 : h3;
    float acc = 0.f;
    int curg = batch[n0];
    for (int n = n0; n < n1; ++n) {
        int gid = batch[n];
        if (gid != curg) {
            atomicAdd(&pool[(size_t)curg * 192 + layer * 64 + lane], acc);
            acc = 0.f;
            curg = gid;
        }
        acc += h2f(__builtin_nontemporal_load(hb + (size_t)n * 64 + lane));
    }
    atomicAdd(&pool[(size_t)curg * 192 + layer * 64 + lane], acc);
}

// ---------------- FC head on pooled features ----------------
__global__ void head_kernel(const float* __restrict__ pool,
                            const float* __restrict__ fc1W, const float* __restrict__ fc1b,
                            const float* __restrict__ fc2W, const float* __restrict__ fc2b,
                            float* __restrict__ out) {
    __shared__ float ps[192];
    __shared__ float hs[192];
    int gi = blockIdx.x;
    int t = threadIdx.x;  // 192
    ps[t] = pool[gi * 192 + t];
    __syncthreads();
    float acc = fc1b[t];
#pragma unroll 8
    for (int k = 0; k < 192; ++k) acc = fmaf(ps[k], fc1W[k * 192 + t], acc);
    hs[t] = fmaxf(acc, 0.f);
    __syncthreads();
    if (t == 0) {
        float l0 = fc2b[0], l1 = fc2b[1];
        for (int k = 0; k < 192; ++k) {
            float h = hs[k];
            l0 = fmaf(h, fc2W[k * 2 + 0], l0);
            l1 = fmaf(h, fc2W[k * 2 + 1], l1);
        }
        float mx = fmaxf(l0, l1);
        float lse = mx + logf(expf(l0 - mx) + expf(l1 - mx));
        out[gi * 2 + 0] = l0 - lse;
        out[gi * 2 + 1] = l1 - lse;
    }
}

extern "C" void kernel_launch(void* const* d_in, const int* in_sizes, int n_in,
                              void* d_out, int out_size, void* d_ws, size_t ws_size,
                              hipStream_t stream) {
    const float* x = (const float*)d_in[0];
    const int* src = (const int*)d_in[1];
    const int* dst = (const int*)d_in[2];
    const int* batch = (const int*)d_in[3];
    const float* c1[8];
    const float* c2[8];
    const float* c3[8];
    for (int i = 0; i < 8; ++i) {
        c1[i] = (const float*)d_in[4 + i];
        c2[i] = (const float*)d_in[12 + i];
        c3[i] = (const float*)d_in[20 + i];
    }
    const float* fc1W = (const float*)d_in[28];
    const float* fc1b = (const float*)d_in[29];
    const float* fc2W = (const float*)d_in[30];
    const float* fc2b = (const float*)d_in[31];
    float* out = (float*)d_out;

    // ---- workspace layout (f16 activations; compact CSR) ----
    unsigned short* base = (unsigned short*)d_ws;
    const size_t NA = (size_t)NNODES * 64;
    unsigned short* xh  = base;                          // N*16
    unsigned short* h1  = xh + (size_t)NNODES * NFP;     // N*64
    unsigned short* h2  = h1 + NA;                       // N*64
    unsigned short* h3  = h2 + NA;                       // N*64
    unsigned short* wfrag = h3 + NA;                     // 3*8192 (16B-aligned)
    float* pool = (float*)(wfrag + 3 * 8192);            // G*192 fp32
    int* ibase = (int*)(pool + (size_t)NG * 192);
    int* rowptr  = ibase;                                // N+1
    int* gcount  = rowptr + NNODES + 1;                  // NBUCK
    int* csre    = gcount + NBUCK + 63;                  // NEDGES (compact)
    int* pairout = csre + NEDGES + 256;                  // NPBLK*PTILE (16B-aligned)
    int* bseg    = pairout + (size_t)NPBLK * PTILE;      // NPBLK*NBUCK

    (void)hipMemsetAsync(gcount, 0, NBUCK * sizeof(int), stream);
    (void)hipMemsetAsync(pool, 0, (size_t)NG * 192 * sizeof(float), stream);

    // ---- CSR build: block counting-sort + per-bucket in-LDS sort (compact CSR) ----
    block_sort_kernel<<<NPBLK, 256, 0, stream>>>(src, dst, pairout, bseg, gcount);
    prep_kernel<<<12 + CVTB, 256, 0, stream>>>(
        x, xh, c1[0], c1[6], c2[0], c2[6], c3[0], c3[6], wfrag);
    bucket_sort_kernel<<<NBUCK, 1024, 0, stream>>>(pairout, bseg, gcount, rowptr, csre);

    // ---- three fused GIN layers (agg + MLP through LDS) ----
    gin_layer_kernel<1><<<NTILES, 256, 0, stream>>>(
        xh, rowptr, csre, wfrag + 0 * 8192,
        c1[1], c1[2], c1[3], c1[4], c1[5], c1[7], h1);
    gin_layer_kernel<2><<<NTILES, 256, 0, stream>>>(
        h1, rowptr, csre, wfrag + 1 * 8192,
        c2[1], c2[2], c2[3], c2[4], c2[5], c2[7], h2);
    gin_layer_kernel<2><<<NTILES, 256, 0, stream>>>(
        h2, rowptr, csre, wfrag + 2 * 8192,
        c3[1], c3[2], c3[3], c3[4], c3[5], c3[7], h3);

    // ---- pooling (one wave per layer-chunk) + FC head ----
    pool_kernel<<<(NPTASK + 3) / 4, 256, 0, stream>>>(h1, h2, h3, batch, pool);
    head_kernel<<<NG, 192, 0, stream>>>(pool, fc1W, fc1b, fc2W, fc2b, out);
}

// Round 11
// 443.896 us; speedup vs baseline: 1.3767x; 1.0057x over previous
//
#include <hip/hip_runtime.h>

#define NNODES 100000
#define NEDGES 3200000
#define NF 13
#define NFP 16       // padded f16 row stride for x
#define NG 512
#define BN_EPS 1e-5f
#define NTILES (NNODES / 16)   // 6250 exactly

#define BSH 9                          // bucket = 512 dst nodes
#define NBUCK ((NNODES + 511) / 512)   // 196
#define PTILE 4096
#define NPBLK ((NEDGES + PTILE - 1) / PTILE)  // 782
#define EPT (PTILE / 256)              // 16 edges per thread in phase A
#define SCAP 17664                     // per-bucket edge cap (mean 16384, +10 sigma)
#define CVTB 200                       // cvt-role blocks in prep_sort
#define K1B (NPBLK + 12 + CVTB)        // 994 blocks total

typedef __attribute__((ext_vector_type(8))) _Float16 f16x8;
typedef __attribute__((ext_vector_type(4))) _Float16 f16x4;
typedef __attribute__((ext_vector_type(4))) float f32x4;
typedef __attribute__((ext_vector_type(4))) int i32x4;

__device__ __forceinline__ unsigned short f2h(float f) {
    union { _Float16 h; unsigned short u; } c;
    c.h = (_Float16)f;   // v_cvt_f16_f32, RNE
    return c.u;
}
__device__ __forceinline__ float h2f(unsigned short u) {
    union { _Float16 h; unsigned short u; } c;
    c.u = u;
    return (float)c.h;   // v_cvt_f32_f16
}

// packed-f16 cross-lane xor-shuffles (shuffle the dwords, add packed)
__device__ __forceinline__ f16x8 shfl_xor8(f16x8 v, int m) {
    union { f16x8 h; int i[4]; } a, b;
    a.h = v;
#pragma unroll
    for (int k = 0; k < 4; ++k) b.i[k] = __shfl_xor(a.i[k], m, 64);
    return b.h;
}
__device__ __forceinline__ f16x4 shfl_xor4(f16x4 v, int m) {
    union { f16x4 h; int i[2]; } a, b;
    a.h = v;
#pragma unroll
    for (int k = 0; k < 2; ++k) b.i[k] = __shfl_xor(a.i[k], m, 64);
    return b.h;
}

// ---------------- K1: edge block-sort (0..781) | weight frags (782..793) | cvt --------
__launch_bounds__(256)
__global__ void prep_sort_kernel(const int* __restrict__ src, const int* __restrict__ dst,
                                 int* __restrict__ pairout, int* __restrict__ bseg,
                                 const float* __restrict__ x, unsigned short* __restrict__ xh,
                                 const float* __restrict__ w10, const float* __restrict__ w20,
                                 const float* __restrict__ w11, const float* __restrict__ w21,
                                 const float* __restrict__ w12, const float* __restrict__ w22,
                                 unsigned short* __restrict__ wfrag) {
    __shared__ int hist[256];      // bucket counts -> cursors
    __shared__ int scanbuf[256];
    __shared__ int spair[PTILE];   // 16 KB sorted pairs
    int t = threadIdx.x;
    int bid = blockIdx.x;

    if (bid < NPBLK) {
        // ---- per-block counting sort of 4096 edges by 512-node bucket ----
        int base = bid * PTILE;
        int cnt = NEDGES - base; if (cnt > PTILE) cnt = PTILE;
        int v[EPT], b[EPT];
#pragma unroll
        for (int j = 0; j < EPT; ++j) {
            int i = t + j * 256;
            if (i < cnt) {
                int d = __builtin_nontemporal_load(dst + base + i);
                int s = __builtin_nontemporal_load(src + base + i);
                b[j] = d >> BSH;
                v[j] = ((d & 511) << 17) | s;
            } else b[j] = -1;
        }
        hist[t] = 0;
        __syncthreads();
#pragma unroll
        for (int j = 0; j < EPT; ++j)
            if (b[j] >= 0) atomicAdd(&hist[b[j]], 1);
        __syncthreads();
        // exclusive scan over the 256 bucket slots (Hillis-Steele)
        int val = hist[t];
        scanbuf[t] = val;
        __syncthreads();
        for (int off = 1; off < 256; off <<= 1) {
            int add = (t >= off) ? scanbuf[t - off] : 0;
            __syncthreads();
            scanbuf[t] += add;
            __syncthreads();
        }
        int excl = scanbuf[t] - val;   // exclusive prefix
        if (t < NBUCK) bseg[(size_t)bid * NBUCK + t] = (excl << 13) | val;
        hist[t] = excl;                // reuse hist as scatter cursor
        __syncthreads();
#pragma unroll
        for (int j = 0; j < EPT; ++j) {
            if (b[j] >= 0) {
                int pos = atomicAdd(&hist[b[j]], 1);
                spair[pos] = v[j];
            }
        }
        __syncthreads();
        // coalesced 16B writeout of the sorted block
        const i32x4* sp4 = (const i32x4*)spair;
        i32x4* po4 = (i32x4*)(pairout + (size_t)bid * PTILE);
        for (int j = t; j < PTILE / 4; j += 256)
            __builtin_nontemporal_store(sp4[j], po4 + j);
    } else if (bid < NPBLK + 12) {
        // ---- build MFMA B-fragments for all layer weights (f16) ----
        int tid = (bid - NPBLK) * 256 + t;  // 3072 total
        if (tid >= 3072) return;
        int layer = tid >> 10;
        int rem = tid & 1023;
        int mat = rem >> 9;
        int tile = (rem >> 7) & 3;
        int chunk = (rem >> 6) & 1;
        int lane = rem & 63;
        int quad = lane >> 4, n = lane & 15;
        const float* W = (layer == 0) ? (mat ? w20 : w10)
                       : (layer == 1) ? (mat ? w21 : w11)
                                      : (mat ? w22 : w12);
        int K = (layer == 0 && mat == 0) ? NF : 64;
        unsigned short* o = wfrag + ((size_t)tid) * 8;
#pragma unroll
        for (int j = 0; j < 8; ++j) {
            int k = chunk * 32 + quad * 8 + j;
            float val = (k < K) ? W[k * 64 + tile * 16 + n] : 0.f;
            o[j] = f2h(val);
        }
    } else {
        // ---- convert x (fp32, stride 13) -> xh (f16, stride 16, zero-padded) ----
        const int total = NNODES * NFP;
        int idx = (bid - NPBLK - 12) * 256 + t;
        int stride = CVTB * 256;
        for (int i = idx; i < total; i += stride) {
            int n = i >> 4;
            int f = i & 15;
            xh[i] = (f < NF) ? f2h(__builtin_nontemporal_load(x + n * NF + f))
                             : (unsigned short)0;
        }
    }
}

// ---------------- K2: per-bucket in-LDS counting sort -> compact CSR ------------------
// One 1024-thread block per bucket; per-bucket base bk*SCAP (no global prefix needed).
// Writes per-node (beg,end) as int2 rowse[n] and the bucket's edge list contiguously.
__launch_bounds__(1024)
__global__ void bucket_sort_kernel(const int* __restrict__ pairout,
                                   const int* __restrict__ bseg,
                                   int2* __restrict__ rowse,
                                   int* __restrict__ csre) {
    __shared__ int scanbuf[1024];
    __shared__ int soff[NPBLK];
    __shared__ int hcur[512];
    __shared__ int shv[1];         // total edges in bucket
    __shared__ int spair[SCAP];
    __shared__ int ssort[SCAP];
    int bk = blockIdx.x;
    int t = threadIdx.x;
    int lo = bk << BSH;
    int wave = t >> 6, lane = t & 63;
    int bbase = bk * SCAP;

    // ---- scan: per-segment LDS offsets ----
    int c = (t < NPBLK) ? (bseg[(size_t)t * NBUCK + bk] & 8191) : 0;
    scanbuf[t] = c;
    __syncthreads();
    for (int off = 1; off < 1024; off <<= 1) {
        int a = (t >= off) ? scanbuf[t - off] : 0;
        __syncthreads();
        scanbuf[t] += a;
        __syncthreads();
    }
    if (t < NPBLK) soff[t] = scanbuf[t] - c;
    if (t == NPBLK - 1) shv[0] = scanbuf[t];
    __syncthreads();
    int total = shv[0]; if (total > SCAP) total = SCAP;

    // ---- wave-cooperative segment copy into spair (coalesced reads) ----
    for (int k = wave; k < NPBLK; k += 16) {
        int pk = bseg[(size_t)k * NBUCK + bk];
        int cnt = pk & 8191;
        const int* seg = pairout + (size_t)k * PTILE + (pk >> 13);
        int dsto = soff[k];
        for (int i = lane; i < cnt; i += 64)
            if (dsto + i < SCAP) spair[dsto + i] = __builtin_nontemporal_load(seg + i);
    }
    if (t < 512) hcur[t] = 0;
    __syncthreads();

    // ---- 512-bin histogram ----
    for (int i = t; i < total; i += 1024) atomicAdd(&hcur[spair[i] >> 17], 1);
    __syncthreads();

    // ---- scan node offsets within bucket; write rowse ----
    int hv = (t < 512) ? hcur[t] : 0;
    scanbuf[t] = hv;
    __syncthreads();
    for (int off = 1; off < 1024; off <<= 1) {
        int a = (t >= off) ? scanbuf[t - off] : 0;
        __syncthreads();
        scanbuf[t] += a;
        __syncthreads();
    }
    if (t < 512) {
        int excl = scanbuf[t] - hv;
        hcur[t] = excl;
        if (lo + t < NNODES) {
            int2 se; se.x = bbase + excl; se.y = bbase + excl + hv;
            rowse[lo + t] = se;
        }
    }
    __syncthreads();

    // ---- LDS scatter into sorted order ----
    for (int i = t; i < total; i += 1024) {
        int p = spair[i];
        int pos = atomicAdd(&hcur[p >> 17], 1);
        ssort[pos] = p & 0x1FFFF;
    }
    __syncthreads();

    // ---- coalesced writeout of the bucket's compact edge list ----
    for (int i = t; i < total; i += 1024)
        __builtin_nontemporal_store(ssort[i], csre + bbase + i);
}

// ---------------- fused GIN layer: pair-gather + MFMA MLP through LDS -----------------
template <int LAYER>   // 1: fin=13 (xh, stride 16, K=32); 2: fin=64 (h, stride 64, K=64)
__launch_bounds__(256, 4)
__global__ void gin_layer_kernel(const unsigned short* __restrict__ xin,
                                 const int2* __restrict__ rowse,
                                 const int* __restrict__ csr,
                                 const unsigned short* __restrict__ wfrag,
                                 const float* __restrict__ b1, const float* __restrict__ gam,
                                 const float* __restrict__ be, const float* __restrict__ mu,
                                 const float* __restrict__ var, const float* __restrict__ b2,
                                 unsigned short* __restrict__ hout) {
    constexpr int FSTR = (LAYER == 1) ? NFP : 64;
    __shared__ __align__(16) unsigned short ytile[16][80];  // agg rows, 160B stride
    __shared__ __align__(16) unsigned short ztile[16][80];  // hidden rows
    int lane = threadIdx.x & 63;
    int wid = threadIdx.x >> 6;
    int quad = lane >> 4, n16 = lane & 15;
    int nb = blockIdx.x * 16;

    // ---------------- aggregation phase ----------------
    if constexpr (LAYER == 1) {
        int g = lane >> 2;   // edge slot within 16-edge gather
        int r = lane & 3;    // row chunk: features r*4 .. r*4+3
#pragma unroll
        for (int pp = 0; pp < 2; ++pp) {
            int lnA = wid * 4 + pp * 2;
            int nA = nb + lnA, nB = nA + 1;
            int2 seA = rowse[nA];
            int2 seB = rowse[nB];
            int jA = seA.x, endA = seA.y;
            int jB = seB.x, endB = seB.y;
            f16x4 accA = {0, 0, 0, 0};
            f16x4 accB = {0, 0, 0, 0};
            if (g == 0) {  // self rows, added once
                accA = *(const f16x4*)&xin[(size_t)nA * FSTR + r * 4];
                accB = *(const f16x4*)&xin[(size_t)nB * FSTR + r * 4];
            }
            while (jA + 16 <= endA && jB + 16 <= endB) {
                int iA = __builtin_nontemporal_load(csr + jA + g);
                int iB = __builtin_nontemporal_load(csr + jB + g);
                f16x4 vA = *(const f16x4*)&xin[(size_t)iA * FSTR + r * 4];
                f16x4 vB = *(const f16x4*)&xin[(size_t)iB * FSTR + r * 4];
                accA += vA; accB += vB;
                jA += 16; jB += 16;
            }
            for (; jA + 32 <= endA; jA += 32) {
                int i0 = __builtin_nontemporal_load(csr + jA + g);
                int i1 = __builtin_nontemporal_load(csr + jA + 16 + g);
                f16x4 v0 = *(const f16x4*)&xin[(size_t)i0 * FSTR + r * 4];
                f16x4 v1 = *(const f16x4*)&xin[(size_t)i1 * FSTR + r * 4];
                accA += v0; accA += v1;
            }
            for (; jA < endA; jA += 16) {
                int e = jA + g;
                if (e < endA) {
                    int i0 = __builtin_nontemporal_load(csr + e);
                    accA += *(const f16x4*)&xin[(size_t)i0 * FSTR + r * 4];
                }
            }
            for (; jB + 32 <= endB; jB += 32) {
                int i0 = __builtin_nontemporal_load(csr + jB + g);
                int i1 = __builtin_nontemporal_load(csr + jB + 16 + g);
                f16x4 v0 = *(const f16x4*)&xin[(size_t)i0 * FSTR + r * 4];
                f16x4 v1 = *(const f16x4*)&xin[(size_t)i1 * FSTR + r * 4];
                accB += v0; accB += v1;
            }
            for (; jB < endB; jB += 16) {
                int e = jB + g;
                if (e < endB) {
                    int i0 = __builtin_nontemporal_load(csr + e);
                    accB += *(const f16x4*)&xin[(size_t)i0 * FSTR + r * 4];
                }
            }
#pragma unroll
            for (int m = 4; m < 64; m <<= 1) {
                accA += shfl_xor4(accA, m);
                accB += shfl_xor4(accB, m);
            }
            if (g == 0) {
                *(f16x4*)&ytile[lnA][r * 4] = accA;
                *(f16x4*)&ytile[lnA + 1][r * 4] = accB;
            } else if (g == 1) {  // zero-pad cols 16..31 (K=32 MFMA chunk)
                f16x4 z = {0, 0, 0, 0};
                *(f16x4*)&ytile[lnA][16 + r * 4] = z;
                *(f16x4*)&ytile[lnA + 1][16 + r * 4] = z;
            }
        }
    } else {
        int g = lane >> 3;   // edge slot within 8-edge gather
        int r = lane & 7;    // row chunk: features r*8 .. r*8+7
#pragma unroll
        for (int pp = 0; pp < 2; ++pp) {
            int lnA = wid * 4 + pp * 2;
            int nA = nb + lnA, nB = nA + 1;
            int2 seA = rowse[nA];
            int2 seB = rowse[nB];
            int jA = seA.x, endA = seA.y;
            int jB = seB.x, endB = seB.y;
            f16x8 accA = {0, 0, 0, 0, 0, 0, 0, 0};
            f16x8 accB = {0, 0, 0, 0, 0, 0, 0, 0};
            if (g == 0) {  // self rows, added once
                accA = *(const f16x8*)&xin[(size_t)nA * 64 + r * 8];
                accB = *(const f16x8*)&xin[(size_t)nB * 64 + r * 8];
            }
            while (jA + 16 <= endA && jB + 16 <= endB) {
                int iA0 = __builtin_nontemporal_load(csr + jA + g);
                int iA1 = __builtin_nontemporal_load(csr + jA + 8 + g);
                int iB0 = __builtin_nontemporal_load(csr + jB + g);
                int iB1 = __builtin_nontemporal_load(csr + jB + 8 + g);
                f16x8 vA0 = *(const f16x8*)&xin[(size_t)iA0 * 64 + r * 8];
                f16x8 vA1 = *(const f16x8*)&xin[(size_t)iA1 * 64 + r * 8];
                f16x8 vB0 = *(const f16x8*)&xin[(size_t)iB0 * 64 + r * 8];
                f16x8 vB1 = *(const f16x8*)&xin[(size_t)iB1 * 64 + r * 8];
                accA += vA0; accA += vA1;
                accB += vB0; accB += vB1;
                jA += 16; jB += 16;
            }
            for (; jA + 16 <= endA; jA += 16) {
                int i0 = __builtin_nontemporal_load(csr + jA + g);
                int i1 = __builtin_nontemporal_load(csr + jA + 8 + g);
                f16x8 v0 = *(const f16x8*)&xin[(size_t)i0 * 64 + r * 8];
                f16x8 v1 = *(const f16x8*)&xin[(size_t)i1 * 64 + r * 8];
                accA += v0; accA += v1;
            }
            for (; jA < endA; jA += 8) {
                int e = jA + g;
                if (e < endA) {
                    int i0 = __builtin_nontemporal_load(csr + e);
                    accA += *(const f16x8*)&xin[(size_t)i0 * 64 + r * 8];
                }
            }
            for (; jB + 16 <= endB; jB += 16) {
                int i0 = __builtin_nontemporal_load(csr + jB + g);
                int i1 = __builtin_nontemporal_load(csr + jB + 8 + g);
                f16x8 v0 = *(const f16x8*)&xin[(size_t)i0 * 64 + r * 8];
                f16x8 v1 = *(const f16x8*)&xin[(size_t)i1 * 64 + r * 8];
                accB += v0; accB += v1;
            }
            for (; jB < endB; jB += 8) {
                int e = jB + g;
                if (e < endB) {
                    int i0 = __builtin_nontemporal_load(csr + e);
                    accB += *(const f16x8*)&xin[(size_t)i0 * 64 + r * 8];
                }
            }
#pragma unroll
            for (int m = 8; m < 64; m <<= 1) {
                accA += shfl_xor8(accA, m);
                accB += shfl_xor8(accB, m);
            }
            if (g == 0) {
                *(f16x8*)&ytile[lnA][r * 8] = accA;
                *(f16x8*)&ytile[lnA + 1][r * 8] = accB;
            }
        }
    }

    // ---- load per-wave weight fragments + BN constants (L2-hot; overlaps barrier) ----
    const f16x8* wf = (const f16x8*)wfrag;
    f16x8 w1f0 = wf[((0 * 4 + wid) * 2 + 0) * 64 + lane];
    f16x8 w1f1 = (LAYER == 2) ? wf[((0 * 4 + wid) * 2 + 1) * 64 + lane] : w1f0;
    f16x8 w2f0 = wf[((1 * 4 + wid) * 2 + 0) * 64 + lane];
    f16x8 w2f1 = wf[((1 * 4 + wid) * 2 + 1) * 64 + lane];
    int f = wid * 16 + n16;
    float sc = gam[f] * rsqrtf(var[f] + BN_EPS);
    float sh = (b1[f] - mu[f]) * sc + be[f];
    float bb2 = b2[f];

    __syncthreads();

    // ---------------- MLP: Linear1 + BN + ReLU -> ztile ----------------
    f16x8 a0 = *(const f16x8*)&ytile[n16][quad * 8];
    f32x4 z4 = {0.f, 0.f, 0.f, 0.f};
    z4 = __builtin_amdgcn_mfma_f32_16x16x32_f16(a0, w1f0, z4, 0, 0, 0);
    if constexpr (LAYER == 2) {
        f16x8 a1 = *(const f16x8*)&ytile[n16][32 + quad * 8];
        z4 = __builtin_amdgcn_mfma_f32_16x16x32_f16(a1, w1f1, z4, 0, 0, 0);
    }
#pragma unroll
    for (int reg = 0; reg < 4; ++reg) {
        float z = fmaxf(fmaf(z4[reg], sc, sh), 0.f);
        ztile[quad * 4 + reg][wid * 16 + n16] = f2h(z);
    }
    __syncthreads();

    // ---------------- MLP: Linear2 + ReLU -> global h ----------------
    f16x8 az0 = *(const f16x8*)&ztile[n16][quad * 8];
    f16x8 az1 = *(const f16x8*)&ztile[n16][32 + quad * 8];
    f32x4 h4 = {0.f, 0.f, 0.f, 0.f};
    h4 = __builtin_amdgcn_mfma_f32_16x16x32_f16(az0, w2f0, h4, 0, 0, 0);
    h4 = __builtin_amdgcn_mfma_f32_16x16x32_f16(az1, w2f1, h4, 0, 0, 0);
#pragma unroll
    for (int reg = 0; reg < 4; ++reg) {
        float h = fmaxf(h4[reg] + bb2, 0.f);
        hout[(size_t)(nb + quad * 4 + reg) * 64 + wid * 16 + n16] = f2h(h);
    }
}

// ---------------- K6: pooling + FC head fused (one block per graph) -------------------
// batch is sorted, so each graph's nodes are a contiguous range: binary-search it,
// pool in registers (streaming reads), then the small FC. No pool buffer, no atomics.
__launch_bounds__(192)
__global__ void poolhead_kernel(const unsigned short* __restrict__ h1,
                                const unsigned short* __restrict__ h2,
                                const unsigned short* __restrict__ h3,
                                const int* __restrict__ batch,
                                const float* __restrict__ fc1W, const float* __restrict__ fc1b,
                                const float* __restrict__ fc2W, const float* __restrict__ fc2b,
                                float* __restrict__ out) {
    __shared__ float ps[192];
    __shared__ float hs[192];
    int gi = blockIdx.x;
    int t = threadIdx.x;  // 192

    // lower_bound(batch, gi) and lower_bound(batch, gi+1), redundantly per-thread
    int l = 0, r = NNODES;
    while (l < r) { int m = (l + r) >> 1; if (batch[m] < gi) l = m + 1; else r = m; }
    int lo = l;
    r = NNODES;
    while (l < r) { int m = (l + r) >> 1; if (batch[m] < gi + 1) l = m + 1; else r = m; }
    int hi = l;

    int layer = t >> 6, lane = t & 63;
    const unsigned short* hb = (layer == 0) ? h1 : (layer == 1) ? h2 : h3;
    float acc = 0.f;
    for (int n = lo; n < hi; ++n)
        acc += h2f(__builtin_nontemporal_load(hb + (size_t)n * 64 + lane));
    ps[t] = acc;
    __syncthreads();

    float a = fc1b[t];
#pragma unroll 8
    for (int k = 0; k < 192; ++k) a = fmaf(ps[k], fc1W[k * 192 + t], a);
    hs[t] = fmaxf(a, 0.f);
    __syncthreads();
    if (t == 0) {
        float l0 = fc2b[0], l1 = fc2b[1];
        for (int k = 0; k < 192; ++k) {
            float h = hs[k];
            l0 = fmaf(h, fc2W[k * 2 + 0], l0);
            l1 = fmaf(h, fc2W[k * 2 + 1], l1);
        }
        float mx = fmaxf(l0, l1);
        float lse = mx + logf(expf(l0 - mx) + expf(l1 - mx));
        out[gi * 2 + 0] = l0 - lse;
        out[gi * 2 + 1] = l1 - lse;
    }
}

extern "C" void kernel_launch(void* const* d_in, const int* in_sizes, int n_in,
                              void* d_out, int out_size, void* d_ws, size_t ws_size,
                              hipStream_t stream) {
    const float* x = (const float*)d_in[0];
    const int* src = (const int*)d_in[1];
    const int* dst = (const int*)d_in[2];
    const int* batch = (const int*)d_in[3];
    const float* c1[8];
    const float* c2[8];
    const float* c3[8];
    for (int i = 0; i < 8; ++i) {
        c1[i] = (const float*)d_in[4 + i];
        c2[i] = (const float*)d_in[12 + i];
        c3[i] = (const float*)d_in[20 + i];
    }
    const float* fc1W = (const float*)d_in[28];
    const float* fc1b = (const float*)d_in[29];
    const float* fc2W = (const float*)d_in[30];
    const float* fc2b = (const float*)d_in[31];
    float* out = (float*)d_out;

    // ---- workspace layout (f16 activations; per-bucket compact CSR; no memsets) ----
    unsigned short* base = (unsigned short*)d_ws;
    const size_t NA = (size_t)NNODES * 64;
    unsigned short* xh  = base;                          // N*16
    unsigned short* h1  = xh + (size_t)NNODES * NFP;     // N*64
    unsigned short* h2  = h1 + NA;                       // N*64
    unsigned short* h3  = h2 + NA;                       // N*64
    unsigned short* wfrag = h3 + NA;                     // 3*8192 (16B-aligned)
    int* ibase = (int*)(wfrag + 3 * 8192);               // 8B-aligned
    int2* rowse  = (int2*)ibase;                         // N (beg,end)
    int* csre    = ibase + 2 * NNODES;                   // NBUCK*SCAP
    int* pairout = csre + (size_t)NBUCK * SCAP + 256;    // NPBLK*PTILE (16B-aligned)
    int* bseg    = pairout + (size_t)NPBLK * PTILE;      // NPBLK*NBUCK

    // ---- K1: edge block-sort + weight frags + x conversion (one kernel) ----
    prep_sort_kernel<<<K1B, 256, 0, stream>>>(
        src, dst, pairout, bseg, x, xh,
        c1[0], c1[6], c2[0], c2[6], c3[0], c3[6], wfrag);

    // ---- K2: per-bucket in-LDS sort -> compact CSR (rowse + csre) ----
    bucket_sort_kernel<<<NBUCK, 1024, 0, stream>>>(pairout, bseg, rowse, csre);

    // ---- three fused GIN layers (agg + MLP through LDS) ----
    gin_layer_kernel<1><<<NTILES, 256, 0, stream>>>(
        xh, rowse, csre, wfrag + 0 * 8192,
        c1[1], c1[2], c1[3], c1[4], c1[5], c1[7], h1);
    gin_layer_kernel<2><<<NTILES, 256, 0, stream>>>(
        h1, rowse, csre, wfrag + 1 * 8192,
        c2[1], c2[2], c2[3], c2[4], c2[5], c2[7], h2);
    gin_layer_kernel<2><<<NTILES, 256, 0, stream>>>(
        h2, rowse, csre, wfrag + 2 * 8192,
        c3[1], c3[2], c3[3], c3[4], c3[5], c3[7], h3);

    // ---- K6: pooling + FC head (one block per graph) ----
    poolhead_kernel<<<NG, 192, 0, stream>>>(
        h1, h2, h3, batch, fc1W, fc1b, fc2W, fc2b, out);
}

// Round 12
// 413.909 us; speedup vs baseline: 1.4765x; 1.0724x over previous
//
#include <hip/hip_runtime.h>

#define NNODES 100000
#define NEDGES 3200000
#define NF 13
#define NFP 16       // padded f16 row stride for x
#define NG 512
#define BN_EPS 1e-5f
#define NTILES (NNODES / 16)   // 6250 exactly

#define BSH 9                          // bucket = 512 dst nodes
#define NBUCK ((NNODES + 511) / 512)   // 196
#define PTILE 4096
#define NPBLK ((NEDGES + PTILE - 1) / PTILE)  // 782
#define EPT (PTILE / 256)              // 16 edges per thread in phase A
#define SCAP 17664                     // per-bucket edge cap (mean 16384, +10 sigma)
#define CVTB 200                       // cvt-role blocks in prep_sort
#define PZB 8                          // pool-zero-role blocks in prep_sort
#define K1B (NPBLK + 12 + CVTB + PZB)  // 1002 blocks total

#define NCHUNK ((NNODES + 63) / 64)    // 1563 64-node chunks
#define NPTASK (3 * NCHUNK)            // wave-tasks for pooling

typedef __attribute__((ext_vector_type(8))) _Float16 f16x8;
typedef __attribute__((ext_vector_type(4))) _Float16 f16x4;
typedef __attribute__((ext_vector_type(4))) float f32x4;
typedef __attribute__((ext_vector_type(4))) int i32x4;

__device__ __forceinline__ unsigned short f2h(float f) {
    union { _Float16 h; unsigned short u; } c;
    c.h = (_Float16)f;   // v_cvt_f16_f32, RNE
    return c.u;
}
__device__ __forceinline__ float h2f(unsigned short u) {
    union { _Float16 h; unsigned short u; } c;
    c.u = u;
    return (float)c.h;   // v_cvt_f32_f16
}

// packed-f16 cross-lane xor-shuffles (shuffle the dwords, add packed)
__device__ __forceinline__ f16x8 shfl_xor8(f16x8 v, int m) {
    union { f16x8 h; int i[4]; } a, b;
    a.h = v;
#pragma unroll
    for (int k = 0; k < 4; ++k) b.i[k] = __shfl_xor(a.i[k], m, 64);
    return b.h;
}
__device__ __forceinline__ f16x4 shfl_xor4(f16x4 v, int m) {
    union { f16x4 h; int i[2]; } a, b;
    a.h = v;
#pragma unroll
    for (int k = 0; k < 2; ++k) b.i[k] = __shfl_xor(a.i[k], m, 64);
    return b.h;
}

// ---------------- K1: edge block-sort | weight frags | cvt | pool-zero ---------------
__launch_bounds__(256)
__global__ void prep_sort_kernel(const int* __restrict__ src, const int* __restrict__ dst,
                                 int* __restrict__ pairout, int* __restrict__ bseg,
                                 const float* __restrict__ x, unsigned short* __restrict__ xh,
                                 const float* __restrict__ w10, const float* __restrict__ w20,
                                 const float* __restrict__ w11, const float* __restrict__ w21,
                                 const float* __restrict__ w12, const float* __restrict__ w22,
                                 unsigned short* __restrict__ wfrag,
                                 float* __restrict__ pool) {
    __shared__ int hist[256];      // bucket counts -> cursors
    __shared__ int scanbuf[256];
    __shared__ int spair[PTILE];   // 16 KB sorted pairs
    int t = threadIdx.x;
    int bid = blockIdx.x;

    if (bid < NPBLK) {
        // ---- per-block counting sort of 4096 edges by 512-node bucket ----
        int base = bid * PTILE;
        int cnt = NEDGES - base; if (cnt > PTILE) cnt = PTILE;
        int v[EPT], b[EPT];
#pragma unroll
        for (int j = 0; j < EPT; ++j) {
            int i = t + j * 256;
            if (i < cnt) {
                int d = __builtin_nontemporal_load(dst + base + i);
                int s = __builtin_nontemporal_load(src + base + i);
                b[j] = d >> BSH;
                v[j] = ((d & 511) << 17) | s;
            } else b[j] = -1;
        }
        hist[t] = 0;
        __syncthreads();
#pragma unroll
        for (int j = 0; j < EPT; ++j)
            if (b[j] >= 0) atomicAdd(&hist[b[j]], 1);
        __syncthreads();
        // exclusive scan over the 256 bucket slots (Hillis-Steele)
        int val = hist[t];
        scanbuf[t] = val;
        __syncthreads();
        for (int off = 1; off < 256; off <<= 1) {
            int add = (t >= off) ? scanbuf[t - off] : 0;
            __syncthreads();
            scanbuf[t] += add;
            __syncthreads();
        }
        int excl = scanbuf[t] - val;   // exclusive prefix
        if (t < NBUCK) bseg[(size_t)bid * NBUCK + t] = (excl << 13) | val;
        hist[t] = excl;                // reuse hist as scatter cursor
        __syncthreads();
#pragma unroll
        for (int j = 0; j < EPT; ++j) {
            if (b[j] >= 0) {
                int pos = atomicAdd(&hist[b[j]], 1);
                spair[pos] = v[j];
            }
        }
        __syncthreads();
        // coalesced 16B writeout of the sorted block
        const i32x4* sp4 = (const i32x4*)spair;
        i32x4* po4 = (i32x4*)(pairout + (size_t)bid * PTILE);
        for (int j = t; j < PTILE / 4; j += 256)
            __builtin_nontemporal_store(sp4[j], po4 + j);
    } else if (bid < NPBLK + 12) {
        // ---- build MFMA B-fragments for all layer weights (f16) ----
        int tid = (bid - NPBLK) * 256 + t;  // 3072 total
        if (tid >= 3072) return;
        int layer = tid >> 10;
        int rem = tid & 1023;
        int mat = rem >> 9;
        int tile = (rem >> 7) & 3;
        int chunk = (rem >> 6) & 1;
        int lane = rem & 63;
        int quad = lane >> 4, n = lane & 15;
        const float* W = (layer == 0) ? (mat ? w20 : w10)
                       : (layer == 1) ? (mat ? w21 : w11)
                                      : (mat ? w22 : w12);
        int K = (layer == 0 && mat == 0) ? NF : 64;
        unsigned short* o = wfrag + ((size_t)tid) * 8;
#pragma unroll
        for (int j = 0; j < 8; ++j) {
            int k = chunk * 32 + quad * 8 + j;
            float val = (k < K) ? W[k * 64 + tile * 16 + n] : 0.f;
            o[j] = f2h(val);
        }
    } else if (bid < NPBLK + 12 + CVTB) {
        // ---- convert x (fp32, stride 13) -> xh (f16, stride 16, zero-padded) ----
        const int total = NNODES * NFP;
        int idx = (bid - NPBLK - 12) * 256 + t;
        int stride = CVTB * 256;
        for (int i = idx; i < total; i += stride) {
            int n = i >> 4;
            int f = i & 15;
            xh[i] = (f < NF) ? f2h(__builtin_nontemporal_load(x + n * NF + f))
                             : (unsigned short)0;
        }
    } else {
        // ---- zero the pool accumulator (float4 stores) ----
        const int total4 = NG * 192 / 4;   // 24576 float4
        int idx = (bid - NPBLK - 12 - CVTB) * 256 + t;
        int stride = PZB * 256;
        f32x4 z = {0.f, 0.f, 0.f, 0.f};
        f32x4* p4 = (f32x4*)pool;
        for (int i = idx; i < total4; i += stride) p4[i] = z;
    }
}

// ---------------- K2: per-bucket in-LDS counting sort -> compact CSR ------------------
__launch_bounds__(1024)
__global__ void bucket_sort_kernel(const int* __restrict__ pairout,
                                   const int* __restrict__ bseg,
                                   int2* __restrict__ rowse,
                                   int* __restrict__ csre) {
    __shared__ int scanbuf[1024];
    __shared__ int soff[NPBLK];
    __shared__ int hcur[512];
    __shared__ int shv[1];         // total edges in bucket
    __shared__ int spair[SCAP];
    __shared__ int ssort[SCAP];
    int bk = blockIdx.x;
    int t = threadIdx.x;
    int lo = bk << BSH;
    int wave = t >> 6, lane = t & 63;
    int bbase = bk * SCAP;

    // ---- scan: per-segment LDS offsets ----
    int c = (t < NPBLK) ? (bseg[(size_t)t * NBUCK + bk] & 8191) : 0;
    scanbuf[t] = c;
    __syncthreads();
    for (int off = 1; off < 1024; off <<= 1) {
        int a = (t >= off) ? scanbuf[t - off] : 0;
        __syncthreads();
        scanbuf[t] += a;
        __syncthreads();
    }
    if (t < NPBLK) soff[t] = scanbuf[t] - c;
    if (t == NPBLK - 1) shv[0] = scanbuf[t];
    __syncthreads();
    int total = shv[0]; if (total > SCAP) total = SCAP;

    // ---- wave-cooperative segment copy into spair (coalesced reads) ----
    for (int k = wave; k < NPBLK; k += 16) {
        int pk = bseg[(size_t)k * NBUCK + bk];
        int cnt = pk & 8191;
        const int* seg = pairout + (size_t)k * PTILE + (pk >> 13);
        int dsto = soff[k];
        for (int i = lane; i < cnt; i += 64)
            if (dsto + i < SCAP) spair[dsto + i] = __builtin_nontemporal_load(seg + i);
    }
    if (t < 512) hcur[t] = 0;
    __syncthreads();

    // ---- 512-bin histogram ----
    for (int i = t; i < total; i += 1024) atomicAdd(&hcur[spair[i] >> 17], 1);
    __syncthreads();

    // ---- scan node offsets within bucket; write rowse ----
    int hv = (t < 512) ? hcur[t] : 0;
    scanbuf[t] = hv;
    __syncthreads();
    for (int off = 1; off < 1024; off <<= 1) {
        int a = (t >= off) ? scanbuf[t - off] : 0;
        __syncthreads();
        scanbuf[t] += a;
        __syncthreads();
    }
    if (t < 512) {
        int excl = scanbuf[t] - hv;
        hcur[t] = excl;
        if (lo + t < NNODES) {
            int2 se; se.x = bbase + excl; se.y = bbase + excl + hv;
            rowse[lo + t] = se;
        }
    }
    __syncthreads();

    // ---- LDS scatter into sorted order ----
    for (int i = t; i < total; i += 1024) {
        int p = spair[i];
        int pos = atomicAdd(&hcur[p >> 17], 1);
        ssort[pos] = p & 0x1FFFF;
    }
    __syncthreads();

    // ---- coalesced writeout of the bucket's compact edge list ----
    for (int i = t; i < total; i += 1024)
        __builtin_nontemporal_store(ssort[i], csre + bbase + i);
}

// ---------------- fused GIN layer: pair-gather + MFMA MLP through LDS -----------------
template <int LAYER>   // 1: fin=13 (xh, stride 16, K=32); 2: fin=64 (h, stride 64, K=64)
__launch_bounds__(256, 4)
__global__ void gin_layer_kernel(const unsigned short* __restrict__ xin,
                                 const int2* __restrict__ rowse,
                                 const int* __restrict__ csr,
                                 const unsigned short* __restrict__ wfrag,
                                 const float* __restrict__ b1, const float* __restrict__ gam,
                                 const float* __restrict__ be, const float* __restrict__ mu,
                                 const float* __restrict__ var, const float* __restrict__ b2,
                                 unsigned short* __restrict__ hout) {
    constexpr int FSTR = (LAYER == 1) ? NFP : 64;
    __shared__ __align__(16) unsigned short ytile[16][80];  // agg rows, 160B stride
    __shared__ __align__(16) unsigned short ztile[16][80];  // hidden rows
    int lane = threadIdx.x & 63;
    int wid = threadIdx.x >> 6;
    int quad = lane >> 4, n16 = lane & 15;
    int nb = blockIdx.x * 16;

    // ---------------- aggregation phase ----------------
    if constexpr (LAYER == 1) {
        int g = lane >> 2;   // edge slot within 16-edge gather
        int r = lane & 3;    // row chunk: features r*4 .. r*4+3
#pragma unroll
        for (int pp = 0; pp < 2; ++pp) {
            int lnA = wid * 4 + pp * 2;
            int nA = nb + lnA, nB = nA + 1;
            int2 seA = rowse[nA];
            int2 seB = rowse[nB];
            int jA = seA.x, endA = seA.y;
            int jB = seB.x, endB = seB.y;
            f16x4 accA = {0, 0, 0, 0};
            f16x4 accB = {0, 0, 0, 0};
            if (g == 0) {  // self rows, added once
                accA = *(const f16x4*)&xin[(size_t)nA * FSTR + r * 4];
                accB = *(const f16x4*)&xin[(size_t)nB * FSTR + r * 4];
            }
            while (jA + 16 <= endA && jB + 16 <= endB) {
                int iA = __builtin_nontemporal_load(csr + jA + g);
                int iB = __builtin_nontemporal_load(csr + jB + g);
                f16x4 vA = *(const f16x4*)&xin[(size_t)iA * FSTR + r * 4];
                f16x4 vB = *(const f16x4*)&xin[(size_t)iB * FSTR + r * 4];
                accA += vA; accB += vB;
                jA += 16; jB += 16;
            }
            for (; jA + 32 <= endA; jA += 32) {
                int i0 = __builtin_nontemporal_load(csr + jA + g);
                int i1 = __builtin_nontemporal_load(csr + jA + 16 + g);
                f16x4 v0 = *(const f16x4*)&xin[(size_t)i0 * FSTR + r * 4];
                f16x4 v1 = *(const f16x4*)&xin[(size_t)i1 * FSTR + r * 4];
                accA += v0; accA += v1;
            }
            for (; jA < endA; jA += 16) {
                int e = jA + g;
                if (e < endA) {
                    int i0 = __builtin_nontemporal_load(csr + e);
                    accA += *(const f16x4*)&xin[(size_t)i0 * FSTR + r * 4];
                }
            }
            for (; jB + 32 <= endB; jB += 32) {
                int i0 = __builtin_nontemporal_load(csr + jB + g);
                int i1 = __builtin_nontemporal_load(csr + jB + 16 + g);
                f16x4 v0 = *(const f16x4*)&xin[(size_t)i0 * FSTR + r * 4];
                f16x4 v1 = *(const f16x4*)&xin[(size_t)i1 * FSTR + r * 4];
                accB += v0; accB += v1;
            }
            for (; jB < endB; jB += 16) {
                int e = jB + g;
                if (e < endB) {
                    int i0 = __builtin_nontemporal_load(csr + e);
                    accB += *(const f16x4*)&xin[(size_t)i0 * FSTR + r * 4];
                }
            }
#pragma unroll
            for (int m = 4; m < 64; m <<= 1) {
                accA += shfl_xor4(accA, m);
                accB += shfl_xor4(accB, m);
            }
            if (g == 0) {
                *(f16x4*)&ytile[lnA][r * 4] = accA;
                *(f16x4*)&ytile[lnA + 1][r * 4] = accB;
            } else if (g == 1) {  // zero-pad cols 16..31 (K=32 MFMA chunk)
                f16x4 z = {0, 0, 0, 0};
                *(f16x4*)&ytile[lnA][16 + r * 4] = z;
                *(f16x4*)&ytile[lnA + 1][16 + r * 4] = z;
            }
        }
    } else {
        int g = lane >> 3;   // edge slot within 8-edge gather
        int r = lane & 7;    // row chunk: features r*8 .. r*8+7
#pragma unroll
        for (int pp = 0; pp < 2; ++pp) {
            int lnA = wid * 4 + pp * 2;
            int nA = nb + lnA, nB = nA + 1;
            int2 seA = rowse[nA];
            int2 seB = rowse[nB];
            int jA = seA.x, endA = seA.y;
            int jB = seB.x, endB = seB.y;
            f16x8 accA = {0, 0, 0, 0, 0, 0, 0, 0};
            f16x8 accB = {0, 0, 0, 0, 0, 0, 0, 0};
            if (g == 0) {  // self rows, added once
                accA = *(const f16x8*)&xin[(size_t)nA * 64 + r * 8];
                accB = *(const f16x8*)&xin[(size_t)nB * 64 + r * 8];
            }
            while (jA + 16 <= endA && jB + 16 <= endB) {
                int iA0 = __builtin_nontemporal_load(csr + jA + g);
                int iA1 = __builtin_nontemporal_load(csr + jA + 8 + g);
                int iB0 = __builtin_nontemporal_load(csr + jB + g);
                int iB1 = __builtin_nontemporal_load(csr + jB + 8 + g);
                f16x8 vA0 = *(const f16x8*)&xin[(size_t)iA0 * 64 + r * 8];
                f16x8 vA1 = *(const f16x8*)&xin[(size_t)iA1 * 64 + r * 8];
                f16x8 vB0 = *(const f16x8*)&xin[(size_t)iB0 * 64 + r * 8];
                f16x8 vB1 = *(const f16x8*)&xin[(size_t)iB1 * 64 + r * 8];
                accA += vA0; accA += vA1;
                accB += vB0; accB += vB1;
                jA += 16; jB += 16;
            }
            for (; jA + 16 <= endA; jA += 16) {
                int i0 = __builtin_nontemporal_load(csr + jA + g);
                int i1 = __builtin_nontemporal_load(csr + jA + 8 + g);
                f16x8 v0 = *(const f16x8*)&xin[(size_t)i0 * 64 + r * 8];
                f16x8 v1 = *(const f16x8*)&xin[(size_t)i1 * 64 + r * 8];
                accA += v0; accA += v1;
            }
            for (; jA < endA; jA += 8) {
                int e = jA + g;
                if (e < endA) {
                    int i0 = __builtin_nontemporal_load(csr + e);
                    accA += *(const f16x8*)&xin[(size_t)i0 * 64 + r * 8];
                }
            }
            for (; jB + 16 <= endB; jB += 16) {
                int i0 = __builtin_nontemporal_load(csr + jB + g);
                int i1 = __builtin_nontemporal_load(csr + jB + 8 + g);
                f16x8 v0 = *(const f16x8*)&xin[(size_t)i0 * 64 + r * 8];
                f16x8 v1 = *(const f16x8*)&xin[(size_t)i1 * 64 + r * 8];
                accB += v0; accB += v1;
            }
            for (; jB < endB; jB += 8) {
                int e = jB + g;
                if (e < endB) {
                    int i0 = __builtin_nontemporal_load(csr + e);
                    accB += *(const f16x8*)&xin[(size_t)i0 * 64 + r * 8];
                }
            }
#pragma unroll
            for (int m = 8; m < 64; m <<= 1) {
                accA += shfl_xor8(accA, m);
                accB += shfl_xor8(accB, m);
            }
            if (g == 0) {
                *(f16x8*)&ytile[lnA][r * 8] = accA;
                *(f16x8*)&ytile[lnA + 1][r * 8] = accB;
            }
        }
    }

    // ---- load per-wave weight fragments + BN constants (L2-hot; overlaps barrier) ----
    const f16x8* wf = (const f16x8*)wfrag;
    f16x8 w1f0 = wf[((0 * 4 + wid) * 2 + 0) * 64 + lane];
    f16x8 w1f1 = (LAYER == 2) ? wf[((0 * 4 + wid) * 2 + 1) * 64 + lane] : w1f0;
    f16x8 w2f0 = wf[((1 * 4 + wid) * 2 + 0) * 64 + lane];
    f16x8 w2f1 = wf[((1 * 4 + wid) * 2 + 1) * 64 + lane];
    int f = wid * 16 + n16;
    float sc = gam[f] * rsqrtf(var[f] + BN_EPS);
    float sh = (b1[f] - mu[f]) * sc + be[f];
    float bb2 = b2[f];

    __syncthreads();

    // ---------------- MLP: Linear1 + BN + ReLU -> ztile ----------------
    f16x8 a0 = *(const f16x8*)&ytile[n16][quad * 8];
    f32x4 z4 = {0.f, 0.f, 0.f, 0.f};
    z4 = __builtin_amdgcn_mfma_f32_16x16x32_f16(a0, w1f0, z4, 0, 0, 0);
    if constexpr (LAYER == 2) {
        f16x8 a1 = *(const f16x8*)&ytile[n16][32 + quad * 8];
        z4 = __builtin_amdgcn_mfma_f32_16x16x32_f16(a1, w1f1, z4, 0, 0, 0);
    }
#pragma unroll
    for (int reg = 0; reg < 4; ++reg) {
        float z = fmaxf(fmaf(z4[reg], sc, sh), 0.f);
        ztile[quad * 4 + reg][wid * 16 + n16] = f2h(z);
    }
    __syncthreads();

    // ---------------- MLP: Linear2 + ReLU -> global h ----------------
    f16x8 az0 = *(const f16x8*)&ztile[n16][quad * 8];
    f16x8 az1 = *(const f16x8*)&ztile[n16][32 + quad * 8];
    f32x4 h4 = {0.f, 0.f, 0.f, 0.f};
    h4 = __builtin_amdgcn_mfma_f32_16x16x32_f16(az0, w2f0, h4, 0, 0, 0);
    h4 = __builtin_amdgcn_mfma_f32_16x16x32_f16(az1, w2f1, h4, 0, 0, 0);
#pragma unroll
    for (int reg = 0; reg < 4; ++reg) {
        float h = fmaxf(h4[reg] + bb2, 0.f);
        hout[(size_t)(nb + quad * 4 + reg) * 64 + wid * 16 + n16] = f2h(h);
    }
}

// ---------------- pooling: one wave per (layer, 64-node chunk) ----------------
__launch_bounds__(256)
__global__ void pool_kernel(const unsigned short* __restrict__ h1,
                            const unsigned short* __restrict__ h2,
                            const unsigned short* __restrict__ h3,
                            const int* __restrict__ batch,
                            float* __restrict__ pool) {
    int task = blockIdx.x * 4 + (threadIdx.x >> 6);
    if (task >= NPTASK) return;
    int lane = threadIdx.x & 63;
    int layer = task / NCHUNK;
    int c = task - layer * NCHUNK;
    int n0 = c * 64;
    int n1 = n0 + 64; if (n1 > NNODES) n1 = NNODES;
    const unsigned short* hb = (layer == 0) ? h1 : (layer == 1) ? h2 : h3;
    float acc = 0.f;
    int curg = batch[n0];
    for (int n = n0; n < n1; ++n) {
        int gid = batch[n];
        if (gid != curg) {
            atomicAdd(&pool[(size_t)curg * 192 + layer * 64 + lane], acc);
            acc = 0.f;
            curg = gid;
        }
        acc += h2f(__builtin_nontemporal_load(hb + (size_t)n * 64 + lane));
    }
    atomicAdd(&pool[(size_t)curg * 192 + layer * 64 + lane], acc);
}

// ---------------- FC head on pooled features ----------------
__global__ void head_kernel(const float* __restrict__ pool,
                            const float* __restrict__ fc1W, const float* __restrict__ fc1b,
                            const float* __restrict__ fc2W, const float* __restrict__ fc2b,
                            float* __restrict__ out) {
    __shared__ float ps[192];
    __shared__ float hs[192];
    int gi = blockIdx.x;
    int t = threadIdx.x;  // 192
    ps[t] = pool[gi * 192 + t];
    __syncthreads();
    float acc = fc1b[t];
#pragma unroll 8
    for (int k = 0; k < 192; ++k) acc = fmaf(ps[k], fc1W[k * 192 + t], acc);
    hs[t] = fmaxf(acc, 0.f);
    __syncthreads();
    if (t == 0) {
        float l0 = fc2b[0], l1 = fc2b[1];
        for (int k = 0; k < 192; ++k) {
            float h = hs[k];
            l0 = fmaf(h, fc2W[k * 2 + 0], l0);
            l1 = fmaf(h, fc2W[k * 2 + 1], l1);
        }
        float mx = fmaxf(l0, l1);
        float lse = mx + logf(expf(l0 - mx) + expf(l1 - mx));
        out[gi * 2 + 0] = l0 - lse;
        out[gi * 2 + 1] = l1 - lse;
    }
}

extern "C" void kernel_launch(void* const* d_in, const int* in_sizes, int n_in,
                              void* d_out, int out_size, void* d_ws, size_t ws_size,
                              hipStream_t stream) {
    const float* x = (const float*)d_in[0];
    const int* src = (const int*)d_in[1];
    const int* dst = (const int*)d_in[2];
    const int* batch = (const int*)d_in[3];
    const float* c1[8];
    const float* c2[8];
    const float* c3[8];
    for (int i = 0; i < 8; ++i) {
        c1[i] = (const float*)d_in[4 + i];
        c2[i] = (const float*)d_in[12 + i];
        c3[i] = (const float*)d_in[20 + i];
    }
    const float* fc1W = (const float*)d_in[28];
    const float* fc1b = (const float*)d_in[29];
    const float* fc2W = (const float*)d_in[30];
    const float* fc2b = (const float*)d_in[31];
    float* out = (float*)d_out;

    // ---- workspace layout (f16 activations; per-bucket compact CSR; no memsets) ----
    unsigned short* base = (unsigned short*)d_ws;
    const size_t NA = (size_t)NNODES * 64;
    unsigned short* xh  = base;                          // N*16
    unsigned short* h1  = xh + (size_t)NNODES * NFP;     // N*64
    unsigned short* h2  = h1 + NA;                       // N*64
    unsigned short* h3  = h2 + NA;                       // N*64
    unsigned short* wfrag = h3 + NA;                     // 3*8192 (16B-aligned)
    float* pool = (float*)(wfrag + 3 * 8192);            // G*192 fp32 (16B-aligned)
    int* ibase = (int*)(pool + (size_t)NG * 192);
    int2* rowse  = (int2*)ibase;                         // N (beg,end)
    int* csre    = ibase + 2 * NNODES;                   // NBUCK*SCAP
    int* pairout = csre + (size_t)NBUCK * SCAP + 256;    // NPBLK*PTILE (16B-aligned)
    int* bseg    = pairout + (size_t)NPBLK * PTILE;      // NPBLK*NBUCK

    // ---- K1: edge block-sort + weight frags + x conversion + pool-zero ----
    prep_sort_kernel<<<K1B, 256, 0, stream>>>(
        src, dst, pairout, bseg, x, xh,
        c1[0], c1[6], c2[0], c2[6], c3[0], c3[6], wfrag, pool);

    // ---- K2: per-bucket in-LDS sort -> compact CSR (rowse + csre) ----
    bucket_sort_kernel<<<NBUCK, 1024, 0, stream>>>(pairout, bseg, rowse, csre);

    // ---- three fused GIN layers (agg + MLP through LDS) ----
    gin_layer_kernel<1><<<NTILES, 256, 0, stream>>>(
        xh, rowse, csre, wfrag + 0 * 8192,
        c1[1], c1[2], c1[3], c1[4], c1[5], c1[7], h1);
    gin_layer_kernel<2><<<NTILES, 256, 0, stream>>>(
        h1, rowse, csre, wfrag + 1 * 8192,
        c2[1], c2[2], c2[3], c2[4], c2[5], c2[7], h2);
    gin_layer_kernel<2><<<NTILES, 256, 0, stream>>>(
        h2, rowse, csre, wfrag + 2 * 8192,
        c3[1], c3[2], c3[3], c3[4], c3[5], c3[7], h3);

    // ---- pooling (one wave per layer-chunk) + FC head ----
    pool_kernel<<<(NPTASK + 3) / 4, 256, 0, stream>>>(h1, h2, h3, batch, pool);
    head_kernel<<<NG, 192, 0, stream>>>(pool, fc1W, fc1b, fc2W, fc2b, out);
}